// Round 6
// baseline (5397.958 us; speedup 1.0000x reference)
//
#include <hip/hip_runtime.h>
#include <hip/hip_bf16.h>
#include <math.h>

typedef _Float16 f16_t;
typedef _Float16 f16x8 __attribute__((ext_vector_type(8)));
typedef signed char i8x8 __attribute__((ext_vector_type(8)));
typedef float f32x4 __attribute__((ext_vector_type(4)));

#define MFMA_F16 __builtin_amdgcn_mfma_f32_16x16x32_f16

// ---- problem dims ----
#define B_      64
#define N_TOK   197
#define C_      768
#define H_      12
#define DH      64
#define DFF     3072
#define M_VALID (B_*N_TOK)   // 12608
#define M_PAD   12672        // 99*128
#define NP      208          // padded attn rows
#define NKP     224          // padded attn cols (7*32)
#define BH      (B_*H_)      // 768
#define PLDS    232          // P LDS row stride (f16)

// ---- scale slots ----
#define S_WQKV 0
#define S_WPROJ 1
#define S_WFC1 2
#define S_WFC2 3
#define S_LN1 4
#define S_QKV 5
#define S_LMIN 6
#define S_PROJ 7
#define S_R1 8
#define S_LN2 9
#define S_GELU 10
#define S_R2 11

// ---- GEMM epilogue modes ----
#define EPI_AMX   0  // amax of val (no store)
#define EPI_CODE8 1  // fq -> i8 codes (valid rows)
#define EPI_GAMX  2  // gelu -> amax (no store)
#define EPI_GCODE8 3 // gelu -> fq -> i8 codes, zero pads
#define EPI_F32   4  // store f32 val (valid rows)

// ---------------- helpers ----------------
__device__ __forceinline__ float wred_max(float v){
  #pragma unroll
  for (int o = 32; o; o >>= 1) v = fmaxf(v, __shfl_xor(v, o));
  return v;
}
__device__ __forceinline__ float wred_min(float v){
  #pragma unroll
  for (int o = 32; o; o >>= 1) v = fminf(v, __shfl_xor(v, o));
  return v;
}
__device__ __forceinline__ float wred_sum(float v){
  #pragma unroll
  for (int o = 32; o; o >>= 1) v += __shfl_xor(v, o);
  return v;
}
__device__ __forceinline__ void atomicMaxPosF(float* p, float v){
  atomicMax((int*)p, __float_as_int(v));
}
__device__ __forceinline__ float fq_scale(float amax){ return amax / 127.0f + 1e-8f; }
__device__ __forceinline__ float fq_q(float x, float s){   // quant code (clipped)
  return fminf(fmaxf(rintf(x / s), -128.0f), 127.0f);
}
__device__ __forceinline__ float fq_apply(float x, float s){ return fq_q(x, s) * s; }
__device__ __forceinline__ float gelu_f(float v){
  return 0.5f * v * (1.0f + erff(v * 0.70710678118654752440f));
}
__device__ __forceinline__ f16x8 cvt_i8_f16(i8x8 v){
  f16x8 r;
  #pragma unroll
  for (int i = 0; i < 8; ++i) r[i] = (_Float16)(short)v[i];
  return r;
}

// ---------------- small kernels ----------------
__global__ void k_init(float* slots){
  int i = threadIdx.x;
  if (i < 32) slots[i] = 0.0f;
  if (i == S_LMIN) ((unsigned int*)slots)[i] = 0x7F800000u;  // +inf
}

__global__ void k_fill(float* p, long n, float val){
  long i = (long)blockIdx.x * blockDim.x + threadIdx.x;
  long st = (long)gridDim.x * blockDim.x;
  for (; i < n; i += st) p[i] = val;
}

__global__ void k_amax(const float* __restrict__ p, long n, float* slot){
  long i = (long)blockIdx.x * blockDim.x + threadIdx.x;
  long st = (long)gridDim.x * blockDim.x;
  float m = 0.0f;
  for (; i < n; i += st) m = fmaxf(m, fabsf(p[i]));
  m = wred_max(m);
  if ((threadIdx.x & 63) == 0) atomicMaxPosF(slot, m);
}

// weight f32 -> f16 integer codes
__global__ void k_wcode(const float* __restrict__ in, f16_t* __restrict__ out,
                        const float* amax, long n){
  float s = fq_scale(*amax);
  long i = (long)blockIdx.x * blockDim.x + threadIdx.x;
  long st = (long)gridDim.x * blockDim.x;
  for (; i < n; i += st) out[i] = (f16_t)fq_q(in[i], s);
}

__global__ void k_fq_f32(const float* __restrict__ in, float* __restrict__ out,
                         const float* amax, long n){
  float s = fq_scale(*amax);
  long i = (long)blockIdx.x * blockDim.x + threadIdx.x;
  long st = (long)gridDim.x * blockDim.x;
  for (; i < n; i += st) out[i] = fq_apply(in[i], s);
}

// LayerNorm: pass1 amax; pass2 store i8 codes
template<bool STORE>
__global__ __launch_bounds__(64) void k_ln(const float* __restrict__ x,
    const float* __restrict__ g, const float* __restrict__ b,
    signed char* __restrict__ y8, const float* scale_slot, float* amax_slot){
  int row = blockIdx.x, lane = threadIdx.x;
  const float* xr = x + (long)row * C_;
  float v[12]; float s = 0.0f;
  #pragma unroll
  for (int i = 0; i < 12; ++i){ v[i] = xr[lane + 64*i]; s += v[i]; }
  s = wred_sum(s);
  float mean = s / 768.0f;
  float q = 0.0f;
  #pragma unroll
  for (int i = 0; i < 12; ++i){ float d = v[i] - mean; q += d*d; }
  q = wred_sum(q);
  float inv = rsqrtf(q / 768.0f + 1e-6f);
  if (STORE){
    float fs = fq_scale(*scale_slot);
    signed char* yr = y8 + (long)row * C_;
    #pragma unroll
    for (int i = 0; i < 12; ++i){
      int c = lane + 64*i;
      float o = (v[i] - mean) * inv * g[c] + b[c];
      yr[c] = (signed char)(int)fq_q(o, fs);
    }
  } else {
    float mx = 0.0f;
    #pragma unroll
    for (int i = 0; i < 12; ++i){
      int c = lane + 64*i;
      float o = (v[i] - mean) * inv * g[c] + b[c];
      mx = fmaxf(mx, fabsf(o));
    }
    mx = wred_max(mx);
    if (lane == 0) atomicMaxPosF(amax_slot, mx);
  }
}

template<bool FQRAW>
__global__ void k_res(float* __restrict__ raw, const float* amax_raw,
                      const float* __restrict__ xin, float* amax_out, long n){
  float s = 0.0f;
  if (FQRAW) s = fq_scale(*amax_raw);
  long i = (long)blockIdx.x * blockDim.x + threadIdx.x;
  long st = (long)gridDim.x * blockDim.x;
  float mx = 0.0f;
  for (; i < n; i += st){
    float v = raw[i];
    if (FQRAW) v = fq_apply(v, s);
    float r = xin[i] + v;
    raw[i] = r; mx = fmaxf(mx, fabsf(r));
  }
  mx = wred_max(mx);
  if ((threadIdx.x & 63) == 0) atomicMaxPosF(amax_out, mx);
}

// ---------------- code GEMM: val = (A8 codes . W codes)*sA*sW + bias ----------------
// A8: i8 codes [Mpad][K]; W: f16 codes [N][K]; 128x128 tile, 4 waves, BK=32
template<int EPI>
__global__ __launch_bounds__(256) void k_gemm(const signed char* __restrict__ A8,
    const f16_t* __restrict__ W, const float* __restrict__ bias,
    float* __restrict__ Cf, signed char* __restrict__ C8,
    const float* __restrict__ sA, const float* __restrict__ sW,
    const float* __restrict__ sOut, float* __restrict__ amax_slot,
    int Mv, int N, int K){
  __shared__ __align__(16) f16_t As[128*32];
  __shared__ __align__(16) f16_t Ws[128*32];
  const int bm = blockIdx.y * 128, bn = blockIdx.x * 128;
  const int t = threadIdx.x;
  const int lane = t & 63;
  const int wave = t >> 6;
  const int wr = (wave >> 1) * 64, wc = (wave & 1) * 64;
  const int lr = lane & 15, lkb = (lane >> 4) * 8;
  f32x4 acc[4][4] = {};
  for (int k0 = 0; k0 < K; k0 += 32){
    __syncthreads();
    {  // A tile: 128x32 i8 -> f16
      int r = t >> 1, c = (t & 1) << 4;
      long gg = (long)(bm + r)*K + k0 + c;
      i8x8 c0 = *(const i8x8*)&A8[gg];
      i8x8 c1 = *(const i8x8*)&A8[gg + 8];
      *(f16x8*)&As[r*32 + c]     = cvt_i8_f16(c0);
      *(f16x8*)&As[r*32 + c + 8] = cvt_i8_f16(c1);
    }
    #pragma unroll
    for (int n = 0; n < 2; ++n){  // W tile: 128x32 f16
      int p = t*8 + n*2048;
      int r = p >> 5, c = p & 31;
      *(f16x8*)&Ws[p] = *(const f16x8*)&W[(long)(bn + r)*K + k0 + c];
    }
    __syncthreads();
    f16x8 af[4], wf[4];
    #pragma unroll
    for (int i = 0; i < 4; ++i){
      af[i] = *(const f16x8*)&As[(wr + i*16 + lr)*32 + lkb];
      wf[i] = *(const f16x8*)&Ws[(wc + i*16 + lr)*32 + lkb];
    }
    #pragma unroll
    for (int mf = 0; mf < 4; ++mf)
      #pragma unroll
      for (int nf = 0; nf < 4; ++nf)
        acc[mf][nf] = MFMA_F16(af[mf], wf[nf], acc[mf][nf], 0, 0, 0);
  }
  const float sc = fq_scale(*sA) * fq_scale(*sW);
  float fs = 0.0f;
  if (EPI == EPI_CODE8 || EPI == EPI_GCODE8) fs = fq_scale(*sOut);
  float mx = 0.0f;
  const int rl = (lane >> 4) * 4;
  #pragma unroll
  for (int mf = 0; mf < 4; ++mf){
    #pragma unroll
    for (int j = 0; j < 4; ++j){
      int row = bm + wr + mf*16 + rl + j;
      bool valid = row < Mv;
      #pragma unroll
      for (int nf = 0; nf < 4; ++nf){
        int col = bn + wc + nf*16 + lr;
        float v = acc[mf][nf][j] * sc + bias[col];
        if (EPI == EPI_GAMX || EPI == EPI_GCODE8) v = gelu_f(v);
        if (EPI == EPI_AMX || EPI == EPI_GAMX){
          if (valid) mx = fmaxf(mx, fabsf(v));
        } else if (EPI == EPI_CODE8){
          if (valid) C8[(long)row*N + col] = (signed char)(int)fq_q(v, fs);
        } else if (EPI == EPI_GCODE8){
          C8[(long)row*N + col] = valid ? (signed char)(int)fq_q(v, fs) : (signed char)0;
        } else if (EPI == EPI_F32){
          if (valid) Cf[(long)row*N + col] = v;
        }
      }
    }
  }
  if (EPI == EPI_AMX || EPI == EPI_GAMX){
    mx = wred_max(mx);
    if (lane == 0) atomicMaxPosF(amax_slot, mx);
  }
}

// ---------------- proj GEMM: A = exact integer I via hi/lo f16 planes ----------------
// val = ((Ihi + Ilo/2048) . Wcodes) * 2048 * c * sW + bias;  c = sa_P * s_qkv
__global__ __launch_bounds__(256) void k_gemmp(const f16_t* __restrict__ Ahi,
    const f16_t* __restrict__ Alo, const f16_t* __restrict__ W,
    const float* __restrict__ bias, float* __restrict__ Cf,
    const unsigned int* __restrict__ lmin_slot, const float* __restrict__ sQkv,
    const float* __restrict__ sW, float* __restrict__ amax_slot,
    int Mv, int N, int K){
  __shared__ __align__(16) f16_t Ah[128*32];
  __shared__ __align__(16) f16_t Al[128*32];
  __shared__ __align__(16) f16_t Ws[128*32];
  const int bm = blockIdx.y * 128, bn = blockIdx.x * 128;
  const int t = threadIdx.x;
  const int lane = t & 63;
  const int wave = t >> 6;
  const int wr = (wave >> 1) * 64, wc = (wave & 1) * 64;
  const int lr = lane & 15, lkb = (lane >> 4) * 8;
  f32x4 acc[4][4] = {};
  for (int k0 = 0; k0 < K; k0 += 32){
    __syncthreads();
    #pragma unroll
    for (int n = 0; n < 2; ++n){
      int p = t*8 + n*2048;
      int r = p >> 5, c = p & 31;
      *(f16x8*)&Ah[p] = *(const f16x8*)&Ahi[(long)(bm + r)*K + k0 + c];
      *(f16x8*)&Al[p] = *(const f16x8*)&Alo[(long)(bm + r)*K + k0 + c];
      *(f16x8*)&Ws[p] = *(const f16x8*)&W[(long)(bn + r)*K + k0 + c];
    }
    __syncthreads();
    f16x8 ah[4], al[4], wf[4];
    #pragma unroll
    for (int i = 0; i < 4; ++i){
      ah[i] = *(const f16x8*)&Ah[(wr + i*16 + lr)*32 + lkb];
      al[i] = *(const f16x8*)&Al[(wr + i*16 + lr)*32 + lkb];
      wf[i] = *(const f16x8*)&Ws[(wc + i*16 + lr)*32 + lkb];
    }
    #pragma unroll
    for (int mf = 0; mf < 4; ++mf)
      #pragma unroll
      for (int nf = 0; nf < 4; ++nf){
        acc[mf][nf] = MFMA_F16(ah[mf], wf[nf], acc[mf][nf], 0, 0, 0);
        acc[mf][nf] = MFMA_F16(al[mf], wf[nf], acc[mf][nf], 0, 0, 0);
      }
  }
  float sa_p = (1.0f / __uint_as_float(*lmin_slot)) / 127.0f + 1e-8f;
  const float cs = sa_p * fq_scale(*sQkv) * fq_scale(*sW) * 2048.0f;
  float mx = 0.0f;
  const int rl = (lane >> 4) * 4;
  #pragma unroll
  for (int mf = 0; mf < 4; ++mf){
    #pragma unroll
    for (int j = 0; j < 4; ++j){
      int row = bm + wr + mf*16 + rl + j;
      if (row < Mv){
        #pragma unroll
        for (int nf = 0; nf < 4; ++nf){
          int col = bn + wc + nf*16 + lr;
          float v = acc[mf][nf][j] * cs + bias[col];
          Cf[(long)row*N + col] = v;
          mx = fmaxf(mx, fabsf(v));
        }
      }
    }
  }
  mx = wred_max(mx);
  if (lane == 0) atomicMaxPosF(amax_slot, mx);
}

// ---------------- V transpose: vt[bh][d][kn] (f16 codes) from qkv8 ----------------
__global__ __launch_bounds__(64) void k_vtrans(const signed char* __restrict__ qkv8,
                                               f16_t* __restrict__ vt){
  int bh = blockIdx.x; int b = bh / H_, h = bh % H_, d = threadIdx.x;
  long coff = 1536 + h*64 + d;
  for (int m8 = 0; m8 < NKP/8; ++m8){
    f16_t vv[8];
    #pragma unroll
    for (int e = 0; e < 8; ++e){
      int m = m8*8 + e;
      signed char code = (m < N_TOK) ? qkv8[(long)(b*N_TOK + m)*2304 + coff] : (signed char)0;
      vv[e] = (f16_t)(short)code;
    }
    *(f16x8*)&vt[((long)bh*DH + d)*NKP + m8*8] = *(f16x8*)vv;
  }
}

// ---------------- attention pass1 ----------------
__global__ __launch_bounds__(64) void k_attn1(const signed char* __restrict__ qkv8,
    const float* __restrict__ sQkv, float* __restrict__ marr,
    float* __restrict__ larr, unsigned int* lmin_slot){
  int rt = blockIdx.x, bh = blockIdx.y;
  int b = bh / H_, h = bh % H_;
  int lane = threadIdx.x, lr = lane & 15, lkb = (lane >> 4) * 8;
  float sq = fq_scale(*sQkv);
  float s2 = sq * sq * 0.125f;
  int qn = rt*16 + lr; if (qn > N_TOK-1) qn = N_TOK-1;
  long qoff = (long)(b*N_TOK + qn)*2304 + h*64 + lkb;
  f16x8 a0 = cvt_i8_f16(*(const i8x8*)&qkv8[qoff]);
  f16x8 a1 = cvt_i8_f16(*(const i8x8*)&qkv8[qoff + 32]);
  float m[4], l[4];
  #pragma unroll
  for (int j = 0; j < 4; ++j){ m[j] = -1e30f; l[j] = 0.0f; }
  for (int ct = 0; ct < NKP/16; ++ct){
    int kn = ct*16 + lr; int knc = kn > N_TOK-1 ? N_TOK-1 : kn;
    long koff = (long)(b*N_TOK + knc)*2304 + 768 + h*64 + lkb;
    f16x8 b0 = cvt_i8_f16(*(const i8x8*)&qkv8[koff]);
    f16x8 b1 = cvt_i8_f16(*(const i8x8*)&qkv8[koff + 32]);
    f32x4 sacc = {};
    sacc = MFMA_F16(a0, b0, sacc, 0, 0, 0);
    sacc = MFMA_F16(a1, b1, sacc, 0, 0, 0);
    bool cv = kn < N_TOK;
    #pragma unroll
    for (int j = 0; j < 4; ++j){
      float sv = cv ? sacc[j]*s2 : -1e30f;
      float mn = fmaxf(m[j], sv);
      l[j] = l[j]*expf(m[j]-mn) + expf(sv-mn);
      m[j] = mn;
    }
  }
  #pragma unroll
  for (int mask = 1; mask < 16; mask <<= 1){
    #pragma unroll
    for (int j = 0; j < 4; ++j){
      float mo = __shfl_xor(m[j], mask);
      float lo = __shfl_xor(l[j], mask);
      float mn = fmaxf(m[j], mo);
      l[j] = l[j]*expf(m[j]-mn) + lo*expf(mo-mn);
      m[j] = mn;
    }
  }
  float lmn = 3.4e38f;
  #pragma unroll
  for (int j = 0; j < 4; ++j){
    int r = rt*16 + (lane >> 4)*4 + j;
    if (r < N_TOK) lmn = fminf(lmn, l[j]);
    if (lr == 0 && r < NP){ marr[(long)bh*NP + r] = m[j]; larr[(long)bh*NP + r] = l[j]; }
  }
  lmn = wred_min(lmn);
  if (lane == 0) atomicMin(lmin_slot, __float_as_uint(lmn));
}

// ---------------- attention pass2 + PV: P codes in LDS; out = exact I -> hi/lo planes ----------------
__global__ __launch_bounds__(64) void k_attn2pv(const signed char* __restrict__ qkv8,
    const f16_t* __restrict__ vt, const float* __restrict__ sQkv,
    const float* __restrict__ marr, const float* __restrict__ larr,
    const unsigned int* lmin_slot, f16_t* __restrict__ xa_hi, f16_t* __restrict__ xa_lo){
  __shared__ __align__(16) f16_t Pl[16*PLDS];
  int rt = blockIdx.x, bh = blockIdx.y;
  int b = bh / H_, h = bh % H_;
  int lane = threadIdx.x, lr = lane & 15, lkb = (lane >> 4) * 8;
  float sq = fq_scale(*sQkv);
  float s2 = sq * sq * 0.125f;
  float lmin = __uint_as_float(*lmin_slot);
  float sa = (1.0f / lmin) / 127.0f + 1e-8f;
  int qn = rt*16 + lr; if (qn > N_TOK-1) qn = N_TOK-1;
  long qoff = (long)(b*N_TOK + qn)*2304 + h*64 + lkb;
  f16x8 a0 = cvt_i8_f16(*(const i8x8*)&qkv8[qoff]);
  f16x8 a1 = cvt_i8_f16(*(const i8x8*)&qkv8[qoff + 32]);
  int rbase = (lane >> 4)*4;
  float pm[4], pinv[4];
  #pragma unroll
  for (int j = 0; j < 4; ++j){
    int r = rt*16 + rbase + j;
    pm[j] = marr[(long)bh*NP + r];
    pinv[j] = 1.0f / larr[(long)bh*NP + r];
  }
  for (int ct = 0; ct < NKP/16; ++ct){
    int kn = ct*16 + lr; int knc = kn > N_TOK-1 ? N_TOK-1 : kn;
    long koff = (long)(b*N_TOK + knc)*2304 + 768 + h*64 + lkb;
    f16x8 b0 = cvt_i8_f16(*(const i8x8*)&qkv8[koff]);
    f16x8 b1 = cvt_i8_f16(*(const i8x8*)&qkv8[koff + 32]);
    f32x4 sacc = {};
    sacc = MFMA_F16(a0, b0, sacc, 0, 0, 0);
    sacc = MFMA_F16(a1, b1, sacc, 0, 0, 0);
    bool cv = kn < N_TOK;
    #pragma unroll
    for (int j = 0; j < 4; ++j){
      int r = rt*16 + rbase + j;
      float p = 0.0f;
      if (cv && r < N_TOK) p = expf(sacc[j]*s2 - pm[j]) * pinv[j];
      float qp = fminf(rintf(p / sa), 127.0f);     // P >= 0
      Pl[(rbase + j)*PLDS + ct*16 + lr] = (f16_t)qp;
    }
  }
  __syncthreads();
  // PV: I[16 rows][64 d] = Pcodes[16][224] . Vcodes[224][64]  (exact integers)
  f32x4 acc[4] = {};
  for (int k0 = 0; k0 < NKP; k0 += 32){
    f16x8 a = *(const f16x8*)&Pl[lr*PLDS + k0 + lkb];
    #pragma unroll
    for (int nf = 0; nf < 4; ++nf){
      f16x8 bb = *(const f16x8*)&vt[((long)bh*DH + nf*16 + lr)*NKP + k0 + lkb];
      acc[nf] = MFMA_F16(a, bb, acc[nf], 0, 0, 0);
    }
  }
  #pragma unroll
  for (int j = 0; j < 4; ++j){
    int n = rt*16 + rbase + j;
    if (n < N_TOK){
      long orow = (long)(b*N_TOK + n)*C_ + h*DH;
      #pragma unroll
      for (int nf = 0; nf < 4; ++nf){
        float I  = acc[nf][j];                       // exact integer, |I| < 2^22
        float hi = rintf(I * (1.0f/2048.0f));
        float lo = (I - hi * 2048.0f) * (1.0f/2048.0f);  // |lo|<=0.5, f16-exact
        xa_hi[orow + nf*16 + lr] = (f16_t)hi;
        xa_lo[orow + nf*16 + lr] = (f16_t)lo;
      }
    }
  }
}

// ---------------- host ----------------
static inline int cdiv_i(long a, long b){ return (int)((a + b - 1) / b); }

extern "C" void kernel_launch(void* const* d_in, const int* in_sizes, int n_in,
                              void* d_out, int out_size, void* d_ws, size_t ws_size,
                              hipStream_t stream){
  const float* x      = (const float*)d_in[0];
  const float* w_qkv  = (const float*)d_in[1];
  const float* b_qkv  = (const float*)d_in[2];
  const float* w_proj = (const float*)d_in[3];
  const float* b_proj = (const float*)d_in[4];
  const float* w_fc1  = (const float*)d_in[5];
  const float* b_fc1  = (const float*)d_in[6];
  const float* w_fc2  = (const float*)d_in[7];
  const float* b_fc2  = (const float*)d_in[8];
  const float* g1     = (const float*)d_in[9];
  const float* be1    = (const float*)d_in[10];
  const float* g2     = (const float*)d_in[11];
  const float* be2    = (const float*)d_in[12];
  float* out = (float*)d_out;

  // ---- workspace (~115.2 MB) ----
  char* ws = (char*)d_ws;
  size_t off = 0;
  float* slots  = (float*)ws;              off += 1024;
  f16_t* wqkv_c = (f16_t*)(ws + off);      off += (size_t)2304*768*2;
  f16_t* wproj_c= (f16_t*)(ws + off);      off += (size_t)768*768*2;
  f16_t* wfc1_c = (f16_t*)(ws + off);      off += (size_t)3072*768*2;
  f16_t* wfc2_c = (f16_t*)(ws + off);      off += (size_t)768*3072*2;
  signed char* xn8 = (signed char*)(ws + off); off += (size_t)M_PAD*C_;
  char* r1 = ws + off;
  // attn phase
  signed char* qkv8 = (signed char*)r1;                                // 29.05 MB
  f16_t* vtb  = (f16_t*)(r1 + (size_t)M_VALID*2304);                   // 22.02 MB
  float* marr = (float*)(r1 + (size_t)M_VALID*2304 + (size_t)BH*DH*NKP*2);
  float* larr = marr + (size_t)BH*NP;
  size_t xa_off = (size_t)M_VALID*2304 + (size_t)BH*DH*NKP*2 + 2*(size_t)BH*NP*4;
  f16_t* xa_hi = (f16_t*)(r1 + xa_off);                                // 19.46 MB
  f16_t* xa_lo = (f16_t*)(r1 + xa_off + (size_t)M_PAD*C_*2);           // 19.46 MB
  size_t r1_sz = xa_off + 2*(size_t)M_PAD*C_*2;
  // mlp phase (overlays dead attn buffers; xa planes stay live through proj)
  float* x1 = (float*)r1;                                              // 38.73 MB
  signed char* h8 = (signed char*)(r1 + (size_t)M_VALID*C_*4);         // 38.93 MB
  off += r1_sz;
  const size_t NEED = off;

  if (ws_size < NEED){
    k_fill<<<256, 256, 0, stream>>>(out, out_size, 1.0e4f);  // sentinel
    return;
  }

  const long nW1 = (long)2304*768, nW2 = (long)768*768, nW3 = (long)3072*768, nW4 = (long)768*3072;
  const long nXC = (long)M_VALID*C_;
  float* raw = out;   // d_out doubles as f32 raw buffer

  k_init<<<1, 64, 0, stream>>>(slots);
  // zero pads: xn8 tail rows; xa plane tail rows
  hipMemsetAsync(xn8 + (size_t)M_VALID*C_, 0, (size_t)(M_PAD - M_VALID)*C_, stream);
  hipMemsetAsync(xa_hi + (size_t)M_VALID*C_, 0, (size_t)(M_PAD - M_VALID)*C_*2, stream);
  hipMemsetAsync(xa_lo + (size_t)M_VALID*C_, 0, (size_t)(M_PAD - M_VALID)*C_*2, stream);

  // weight codes
  k_amax<<<cdiv_i(nW1,1024), 256, 0, stream>>>(w_qkv, nW1, &slots[S_WQKV]);
  k_amax<<<cdiv_i(nW2,1024), 256, 0, stream>>>(w_proj, nW2, &slots[S_WPROJ]);
  k_amax<<<cdiv_i(nW3,1024), 256, 0, stream>>>(w_fc1, nW3, &slots[S_WFC1]);
  k_amax<<<cdiv_i(nW4,1024), 256, 0, stream>>>(w_fc2, nW4, &slots[S_WFC2]);
  k_wcode<<<cdiv_i(nW1,256), 256, 0, stream>>>(w_qkv, wqkv_c, &slots[S_WQKV], nW1);
  k_wcode<<<cdiv_i(nW2,256), 256, 0, stream>>>(w_proj, wproj_c, &slots[S_WPROJ], nW2);
  k_wcode<<<cdiv_i(nW3,256), 256, 0, stream>>>(w_fc1, wfc1_c, &slots[S_WFC1], nW3);
  k_wcode<<<cdiv_i(nW4,256), 256, 0, stream>>>(w_fc2, wfc2_c, &slots[S_WFC2], nW4);

  // norm1 -> xn codes
  k_ln<false><<<M_VALID, 64, 0, stream>>>(x, g1, be1, nullptr, nullptr, &slots[S_LN1]);
  k_ln<true ><<<M_VALID, 64, 0, stream>>>(x, g1, be1, xn8, &slots[S_LN1], nullptr);

  // qkv: amax pass then code pass
  k_gemm<EPI_AMX><<<dim3(18, 99), 256, 0, stream>>>(xn8, wqkv_c, b_qkv,
      nullptr, nullptr, &slots[S_LN1], &slots[S_WQKV], nullptr, &slots[S_QKV], M_VALID, 2304, 768);
  k_gemm<EPI_CODE8><<<dim3(18, 99), 256, 0, stream>>>(xn8, wqkv_c, b_qkv,
      nullptr, qkv8, &slots[S_LN1], &slots[S_WQKV], &slots[S_QKV], nullptr, M_VALID, 2304, 768);

  // attention
  k_vtrans<<<BH, 64, 0, stream>>>(qkv8, vtb);
  k_attn1<<<dim3(NP/16, BH), 64, 0, stream>>>(qkv8, &slots[S_QKV], marr, larr,
      (unsigned int*)&slots[S_LMIN]);
  k_attn2pv<<<dim3(NP/16, BH), 64, 0, stream>>>(qkv8, vtb, &slots[S_QKV], marr, larr,
      (const unsigned int*)&slots[S_LMIN], xa_hi, xa_lo);

  // proj (exact I) -> raw(=out) + amax; residual1; fq -> x1
  k_gemmp<<<dim3(6, 99), 256, 0, stream>>>(xa_hi, xa_lo, wproj_c, b_proj, raw,
      (const unsigned int*)&slots[S_LMIN], &slots[S_QKV], &slots[S_WPROJ], &slots[S_PROJ],
      M_VALID, 768, 768);
  k_res<true><<<cdiv_i(nXC,256), 256, 0, stream>>>(raw, &slots[S_PROJ], x, &slots[S_R1], nXC);
  k_fq_f32<<<cdiv_i(nXC,256), 256, 0, stream>>>(raw, x1, &slots[S_R1], nXC);

  // norm2 -> xn codes
  k_ln<false><<<M_VALID, 64, 0, stream>>>(x1, g2, be2, nullptr, nullptr, &slots[S_LN2]);
  k_ln<true ><<<M_VALID, 64, 0, stream>>>(x1, g2, be2, xn8, &slots[S_LN2], nullptr);

  // fc1: gelu-amax pass then gelu-code pass
  k_gemm<EPI_GAMX><<<dim3(24, 99), 256, 0, stream>>>(xn8, wfc1_c, b_fc1,
      nullptr, nullptr, &slots[S_LN2], &slots[S_WFC1], nullptr, &slots[S_GELU], M_VALID, 3072, 768);
  k_gemm<EPI_GCODE8><<<dim3(24, 99), 256, 0, stream>>>(xn8, wfc1_c, b_fc1,
      nullptr, h8, &slots[S_LN2], &slots[S_WFC1], &slots[S_GELU], nullptr, M_VALID, 3072, 768);

  // fc2 -> raw(=out); residual2; final fq
  k_gemm<EPI_F32><<<dim3(6, 99), 256, 0, stream>>>(h8, wfc2_c, b_fc2,
      raw, nullptr, &slots[S_GELU], &slots[S_WFC2], nullptr, nullptr, M_VALID, 768, 3072);
  k_res<false><<<cdiv_i(nXC,256), 256, 0, stream>>>(raw, nullptr, x1, &slots[S_R2], nXC);
  k_fq_f32<<<cdiv_i(nXC,256), 256, 0, stream>>>(raw, out, &slots[S_R2], nXC);
}

// Round 7
// 1651.624 us; speedup vs baseline: 3.2683x; 3.2683x over previous
//
#include <hip/hip_runtime.h>
#include <hip/hip_bf16.h>
#include <math.h>

typedef _Float16 f16_t;
typedef _Float16 f16x8 __attribute__((ext_vector_type(8)));
typedef signed char i8x8 __attribute__((ext_vector_type(8)));
typedef float f32x4 __attribute__((ext_vector_type(4)));

#define MFMA_F16 __builtin_amdgcn_mfma_f32_16x16x32_f16

// ---- problem dims ----
#define B_      64
#define N_TOK   197
#define C_      768
#define H_      12
#define DH      64
#define DFF     3072
#define M_VALID (B_*N_TOK)   // 12608
#define M_PAD   12672        // 99*128
#define NP      208          // padded attn rows
#define NKP     224          // padded attn cols (7*32)
#define BH      (B_*H_)      // 768
#define PLDS    232          // P LDS row stride (f16)

// ---- scale slots ----
#define S_WQKV 0
#define S_WPROJ 1
#define S_WFC1 2
#define S_WFC2 3
#define S_LN1 4
#define S_QKV 5
#define S_LMIN 6
#define S_PROJ 7
#define S_R1 8
#define S_LN2 9
#define S_GELU 10
#define S_R2 11

// ---- GEMM epilogue modes ----
#define EPI_AMX   0  // amax of val (no store)
#define EPI_CODE8 1  // fq -> i8 codes (valid rows)
#define EPI_GAMX  2  // gelu -> amax (no store)
#define EPI_GCODE8 3 // gelu -> fq -> i8 codes, zero pads
#define EPI_F32   4  // store f32 val (valid rows)

// ---------------- helpers ----------------
__device__ __forceinline__ float wred_max(float v){
  #pragma unroll
  for (int o = 32; o; o >>= 1) v = fmaxf(v, __shfl_xor(v, o));
  return v;
}
__device__ __forceinline__ float wred_min(float v){
  #pragma unroll
  for (int o = 32; o; o >>= 1) v = fminf(v, __shfl_xor(v, o));
  return v;
}
__device__ __forceinline__ float wred_sum(float v){
  #pragma unroll
  for (int o = 32; o; o >>= 1) v += __shfl_xor(v, o);
  return v;
}
__device__ __forceinline__ void atomicMaxPosF(float* p, float v){
  atomicMax((int*)p, __float_as_int(v));
}
// block-level max (256 threads, 4 waves) -> one atomic per block
__device__ __forceinline__ void block_amax_commit(float m, float* slot){
  __shared__ float smx[4];
  int t = threadIdx.x, wave = t >> 6, lane = t & 63;
  m = wred_max(m);
  if (lane == 0) smx[wave] = m;
  __syncthreads();
  if (t == 0){
    float r = fmaxf(fmaxf(smx[0], smx[1]), fmaxf(smx[2], smx[3]));
    atomicMaxPosF(slot, r);
  }
}
__device__ __forceinline__ float fq_scale(float amax){ return amax / 127.0f + 1e-8f; }
__device__ __forceinline__ float fq_q(float x, float s){   // quant code (clipped)
  return fminf(fmaxf(rintf(x / s), -128.0f), 127.0f);
}
__device__ __forceinline__ float fq_apply(float x, float s){ return fq_q(x, s) * s; }
__device__ __forceinline__ float gelu_f(float v){
  return 0.5f * v * (1.0f + erff(v * 0.70710678118654752440f));
}
__device__ __forceinline__ f16x8 cvt_i8_f16(i8x8 v){
  f16x8 r;
  #pragma unroll
  for (int i = 0; i < 8; ++i) r[i] = (_Float16)(short)v[i];
  return r;
}

// ---------------- small kernels ----------------
__global__ void k_init(float* slots){
  int i = threadIdx.x;
  if (i < 32) slots[i] = 0.0f;
  if (i == S_LMIN) ((unsigned int*)slots)[i] = 0x7F800000u;  // +inf
}

__global__ void k_fill(float* p, long n, float val){
  long i = (long)blockIdx.x * blockDim.x + threadIdx.x;
  long st = (long)gridDim.x * blockDim.x;
  for (; i < n; i += st) p[i] = val;
}

// amax over n floats (n % 4 == 0), float4 grid-stride, 1 atomic/block
__global__ __launch_bounds__(256) void k_amax(const float* __restrict__ p, long n4, float* slot){
  long i = (long)blockIdx.x * blockDim.x + threadIdx.x;
  long st = (long)gridDim.x * blockDim.x;
  const f32x4* p4 = (const f32x4*)p;
  float m = 0.0f;
  for (; i < n4; i += st){
    f32x4 v = p4[i];
    m = fmaxf(m, fmaxf(fmaxf(fabsf(v[0]), fabsf(v[1])), fmaxf(fabsf(v[2]), fabsf(v[3]))));
  }
  block_amax_commit(m, slot);
}

// weight f32 -> f16 integer codes
__global__ void k_wcode(const float* __restrict__ in, f16_t* __restrict__ out,
                        const float* amax, long n){
  float s = fq_scale(*amax);
  long i = (long)blockIdx.x * blockDim.x + threadIdx.x;
  long st = (long)gridDim.x * blockDim.x;
  for (; i < n; i += st) out[i] = (f16_t)fq_q(in[i], s);
}

// fq (f32 -> f32), float4 vectorized (n % 4 == 0)
__global__ __launch_bounds__(256) void k_fq_f32(const float* __restrict__ in,
    float* __restrict__ out, const float* amax, long n4){
  float s = fq_scale(*amax);
  long i = (long)blockIdx.x * blockDim.x + threadIdx.x;
  long st = (long)gridDim.x * blockDim.x;
  const f32x4* in4 = (const f32x4*)in;
  f32x4* out4 = (f32x4*)out;
  for (; i < n4; i += st){
    f32x4 v = in4[i];
    #pragma unroll
    for (int e = 0; e < 4; ++e) v[e] = fq_apply(v[e], s);
    out4[i] = v;
  }
}

// LayerNorm: pass1 amax; pass2 store i8 codes
template<bool STORE>
__global__ __launch_bounds__(64) void k_ln(const float* __restrict__ x,
    const float* __restrict__ g, const float* __restrict__ b,
    signed char* __restrict__ y8, const float* scale_slot, float* amax_slot){
  int row = blockIdx.x, lane = threadIdx.x;
  const float* xr = x + (long)row * C_;
  float v[12]; float s = 0.0f;
  #pragma unroll
  for (int i = 0; i < 12; ++i){ v[i] = xr[lane + 64*i]; s += v[i]; }
  s = wred_sum(s);
  float mean = s / 768.0f;
  float q = 0.0f;
  #pragma unroll
  for (int i = 0; i < 12; ++i){ float d = v[i] - mean; q += d*d; }
  q = wred_sum(q);
  float inv = rsqrtf(q / 768.0f + 1e-6f);
  if (STORE){
    float fs = fq_scale(*scale_slot);
    signed char* yr = y8 + (long)row * C_;
    #pragma unroll
    for (int i = 0; i < 12; ++i){
      int c = lane + 64*i;
      float o = (v[i] - mean) * inv * g[c] + b[c];
      yr[c] = (signed char)(int)fq_q(o, fs);
    }
  } else {
    float mx = 0.0f;
    #pragma unroll
    for (int i = 0; i < 12; ++i){
      int c = lane + 64*i;
      float o = (v[i] - mean) * inv * g[c] + b[c];
      mx = fmaxf(mx, fabsf(o));
    }
    mx = wred_max(mx);
    if (lane == 0) atomicMaxPosF(amax_slot, mx);
  }
}

// residual: raw = xin + (FQRAW ? fq(raw) : raw); amax of result; float4; 1 atomic/block
template<bool FQRAW>
__global__ __launch_bounds__(256) void k_res(float* __restrict__ raw, const float* amax_raw,
                      const float* __restrict__ xin, float* amax_out, long n4){
  float s = 0.0f;
  if (FQRAW) s = fq_scale(*amax_raw);
  long i = (long)blockIdx.x * blockDim.x + threadIdx.x;
  long st = (long)gridDim.x * blockDim.x;
  f32x4* raw4 = (f32x4*)raw;
  const f32x4* xin4 = (const f32x4*)xin;
  float mx = 0.0f;
  for (; i < n4; i += st){
    f32x4 v = raw4[i];
    f32x4 xv = xin4[i];
    #pragma unroll
    for (int e = 0; e < 4; ++e){
      float t = FQRAW ? fq_apply(v[e], s) : v[e];
      float r = xv[e] + t;
      v[e] = r;
      mx = fmaxf(mx, fabsf(r));
    }
    raw4[i] = v;
  }
  block_amax_commit(mx, amax_out);
}

// ---------------- code GEMM: val = (A8 codes . W codes)*sA*sW + bias ----------------
// A8: i8 codes [Mpad][K]; W: f16 codes [N][K]; 128x128 tile, 4 waves, BK=32
template<int EPI>
__global__ __launch_bounds__(256) void k_gemm(const signed char* __restrict__ A8,
    const f16_t* __restrict__ W, const float* __restrict__ bias,
    float* __restrict__ Cf, signed char* __restrict__ C8,
    const float* __restrict__ sA, const float* __restrict__ sW,
    const float* __restrict__ sOut, float* __restrict__ amax_slot,
    int Mv, int N, int K){
  __shared__ __align__(16) f16_t As[128*32];
  __shared__ __align__(16) f16_t Ws[128*32];
  const int bm = blockIdx.y * 128, bn = blockIdx.x * 128;
  const int t = threadIdx.x;
  const int lane = t & 63;
  const int wave = t >> 6;
  const int wr = (wave >> 1) * 64, wc = (wave & 1) * 64;
  const int lr = lane & 15, lkb = (lane >> 4) * 8;
  f32x4 acc[4][4] = {};
  for (int k0 = 0; k0 < K; k0 += 32){
    __syncthreads();
    {  // A tile: 128x32 i8 -> f16
      int r = t >> 1, c = (t & 1) << 4;
      long gg = (long)(bm + r)*K + k0 + c;
      i8x8 c0 = *(const i8x8*)&A8[gg];
      i8x8 c1 = *(const i8x8*)&A8[gg + 8];
      *(f16x8*)&As[r*32 + c]     = cvt_i8_f16(c0);
      *(f16x8*)&As[r*32 + c + 8] = cvt_i8_f16(c1);
    }
    #pragma unroll
    for (int n = 0; n < 2; ++n){  // W tile: 128x32 f16
      int p = t*8 + n*2048;
      int r = p >> 5, c = p & 31;
      *(f16x8*)&Ws[p] = *(const f16x8*)&W[(long)(bn + r)*K + k0 + c];
    }
    __syncthreads();
    f16x8 af[4], wf[4];
    #pragma unroll
    for (int i = 0; i < 4; ++i){
      af[i] = *(const f16x8*)&As[(wr + i*16 + lr)*32 + lkb];
      wf[i] = *(const f16x8*)&Ws[(wc + i*16 + lr)*32 + lkb];
    }
    #pragma unroll
    for (int mf = 0; mf < 4; ++mf)
      #pragma unroll
      for (int nf = 0; nf < 4; ++nf)
        acc[mf][nf] = MFMA_F16(af[mf], wf[nf], acc[mf][nf], 0, 0, 0);
  }
  const float sc = fq_scale(*sA) * fq_scale(*sW);
  float fs = 0.0f;
  if (EPI == EPI_CODE8 || EPI == EPI_GCODE8) fs = fq_scale(*sOut);
  float mx = 0.0f;
  const int rl = (lane >> 4) * 4;
  #pragma unroll
  for (int mf = 0; mf < 4; ++mf){
    #pragma unroll
    for (int j = 0; j < 4; ++j){
      int row = bm + wr + mf*16 + rl + j;
      bool valid = row < Mv;
      #pragma unroll
      for (int nf = 0; nf < 4; ++nf){
        int col = bn + wc + nf*16 + lr;
        float v = acc[mf][nf][j] * sc + bias[col];
        if (EPI == EPI_GAMX || EPI == EPI_GCODE8) v = gelu_f(v);
        if (EPI == EPI_AMX || EPI == EPI_GAMX){
          if (valid) mx = fmaxf(mx, fabsf(v));
        } else if (EPI == EPI_CODE8){
          if (valid) C8[(long)row*N + col] = (signed char)(int)fq_q(v, fs);
        } else if (EPI == EPI_GCODE8){
          C8[(long)row*N + col] = valid ? (signed char)(int)fq_q(v, fs) : (signed char)0;
        } else if (EPI == EPI_F32){
          if (valid) Cf[(long)row*N + col] = v;
        }
      }
    }
  }
  if (EPI == EPI_AMX || EPI == EPI_GAMX){
    mx = wred_max(mx);
    if (lane == 0) atomicMaxPosF(amax_slot, mx);
  }
}

// ---------------- proj GEMM: A = exact integer I via hi/lo f16 planes ----------------
__global__ __launch_bounds__(256) void k_gemmp(const f16_t* __restrict__ Ahi,
    const f16_t* __restrict__ Alo, const f16_t* __restrict__ W,
    const float* __restrict__ bias, float* __restrict__ Cf,
    const unsigned int* __restrict__ lmin_slot, const float* __restrict__ sQkv,
    const float* __restrict__ sW, float* __restrict__ amax_slot,
    int Mv, int N, int K){
  __shared__ __align__(16) f16_t Ah[128*32];
  __shared__ __align__(16) f16_t Al[128*32];
  __shared__ __align__(16) f16_t Ws[128*32];
  const int bm = blockIdx.y * 128, bn = blockIdx.x * 128;
  const int t = threadIdx.x;
  const int lane = t & 63;
  const int wave = t >> 6;
  const int wr = (wave >> 1) * 64, wc = (wave & 1) * 64;
  const int lr = lane & 15, lkb = (lane >> 4) * 8;
  f32x4 acc[4][4] = {};
  for (int k0 = 0; k0 < K; k0 += 32){
    __syncthreads();
    #pragma unroll
    for (int n = 0; n < 2; ++n){
      int p = t*8 + n*2048;
      int r = p >> 5, c = p & 31;
      *(f16x8*)&Ah[p] = *(const f16x8*)&Ahi[(long)(bm + r)*K + k0 + c];
      *(f16x8*)&Al[p] = *(const f16x8*)&Alo[(long)(bm + r)*K + k0 + c];
      *(f16x8*)&Ws[p] = *(const f16x8*)&W[(long)(bn + r)*K + k0 + c];
    }
    __syncthreads();
    f16x8 ah[4], al[4], wf[4];
    #pragma unroll
    for (int i = 0; i < 4; ++i){
      ah[i] = *(const f16x8*)&Ah[(wr + i*16 + lr)*32 + lkb];
      al[i] = *(const f16x8*)&Al[(wr + i*16 + lr)*32 + lkb];
      wf[i] = *(const f16x8*)&Ws[(wc + i*16 + lr)*32 + lkb];
    }
    #pragma unroll
    for (int mf = 0; mf < 4; ++mf)
      #pragma unroll
      for (int nf = 0; nf < 4; ++nf){
        acc[mf][nf] = MFMA_F16(ah[mf], wf[nf], acc[mf][nf], 0, 0, 0);
        acc[mf][nf] = MFMA_F16(al[mf], wf[nf], acc[mf][nf], 0, 0, 0);
      }
  }
  float sa_p = (1.0f / __uint_as_float(*lmin_slot)) / 127.0f + 1e-8f;
  const float cs = sa_p * fq_scale(*sQkv) * fq_scale(*sW) * 2048.0f;
  float mx = 0.0f;
  const int rl = (lane >> 4) * 4;
  #pragma unroll
  for (int mf = 0; mf < 4; ++mf){
    #pragma unroll
    for (int j = 0; j < 4; ++j){
      int row = bm + wr + mf*16 + rl + j;
      if (row < Mv){
        #pragma unroll
        for (int nf = 0; nf < 4; ++nf){
          int col = bn + wc + nf*16 + lr;
          float v = acc[mf][nf][j] * cs + bias[col];
          Cf[(long)row*N + col] = v;
          mx = fmaxf(mx, fabsf(v));
        }
      }
    }
  }
  mx = wred_max(mx);
  if (lane == 0) atomicMaxPosF(amax_slot, mx);
}

// ---------------- V transpose: vt[bh][d][kn] (f16 codes) from qkv8 ----------------
__global__ __launch_bounds__(64) void k_vtrans(const signed char* __restrict__ qkv8,
                                               f16_t* __restrict__ vt){
  int bh = blockIdx.x; int b = bh / H_, h = bh % H_, d = threadIdx.x;
  long coff = 1536 + h*64 + d;
  for (int m8 = 0; m8 < NKP/8; ++m8){
    f16_t vv[8];
    #pragma unroll
    for (int e = 0; e < 8; ++e){
      int m = m8*8 + e;
      signed char code = (m < N_TOK) ? qkv8[(long)(b*N_TOK + m)*2304 + coff] : (signed char)0;
      vv[e] = (f16_t)(short)code;
    }
    *(f16x8*)&vt[((long)bh*DH + d)*NKP + m8*8] = *(f16x8*)vv;
  }
}

// ---------------- attention pass1 ----------------
__global__ __launch_bounds__(64) void k_attn1(const signed char* __restrict__ qkv8,
    const float* __restrict__ sQkv, float* __restrict__ marr,
    float* __restrict__ larr, unsigned int* lmin_slot){
  int rt = blockIdx.x, bh = blockIdx.y;
  int b = bh / H_, h = bh % H_;
  int lane = threadIdx.x, lr = lane & 15, lkb = (lane >> 4) * 8;
  float sq = fq_scale(*sQkv);
  float s2 = sq * sq * 0.125f;
  int qn = rt*16 + lr; if (qn > N_TOK-1) qn = N_TOK-1;
  long qoff = (long)(b*N_TOK + qn)*2304 + h*64 + lkb;
  f16x8 a0 = cvt_i8_f16(*(const i8x8*)&qkv8[qoff]);
  f16x8 a1 = cvt_i8_f16(*(const i8x8*)&qkv8[qoff + 32]);
  float m[4], l[4];
  #pragma unroll
  for (int j = 0; j < 4; ++j){ m[j] = -1e30f; l[j] = 0.0f; }
  for (int ct = 0; ct < NKP/16; ++ct){
    int kn = ct*16 + lr; int knc = kn > N_TOK-1 ? N_TOK-1 : kn;
    long koff = (long)(b*N_TOK + knc)*2304 + 768 + h*64 + lkb;
    f16x8 b0 = cvt_i8_f16(*(const i8x8*)&qkv8[koff]);
    f16x8 b1 = cvt_i8_f16(*(const i8x8*)&qkv8[koff + 32]);
    f32x4 sacc = {};
    sacc = MFMA_F16(a0, b0, sacc, 0, 0, 0);
    sacc = MFMA_F16(a1, b1, sacc, 0, 0, 0);
    bool cv = kn < N_TOK;
    #pragma unroll
    for (int j = 0; j < 4; ++j){
      float sv = cv ? sacc[j]*s2 : -1e30f;
      float mn = fmaxf(m[j], sv);
      l[j] = l[j]*expf(m[j]-mn) + expf(sv-mn);
      m[j] = mn;
    }
  }
  #pragma unroll
  for (int mask = 1; mask < 16; mask <<= 1){
    #pragma unroll
    for (int j = 0; j < 4; ++j){
      float mo = __shfl_xor(m[j], mask);
      float lo = __shfl_xor(l[j], mask);
      float mn = fmaxf(m[j], mo);
      l[j] = l[j]*expf(m[j]-mn) + lo*expf(mo-mn);
      m[j] = mn;
    }
  }
  float lmn = 3.4e38f;
  #pragma unroll
  for (int j = 0; j < 4; ++j){
    int r = rt*16 + (lane >> 4)*4 + j;
    if (r < N_TOK) lmn = fminf(lmn, l[j]);
    if (lr == 0 && r < NP){ marr[(long)bh*NP + r] = m[j]; larr[(long)bh*NP + r] = l[j]; }
  }
  lmn = wred_min(lmn);
  if (lane == 0) atomicMin(lmin_slot, __float_as_uint(lmn));
}

// ---------------- attention pass2 + PV: P codes in LDS; out = exact I -> hi/lo planes ----------------
__global__ __launch_bounds__(64) void k_attn2pv(const signed char* __restrict__ qkv8,
    const f16_t* __restrict__ vt, const float* __restrict__ sQkv,
    const float* __restrict__ marr, const float* __restrict__ larr,
    const unsigned int* lmin_slot, f16_t* __restrict__ xa_hi, f16_t* __restrict__ xa_lo){
  __shared__ __align__(16) f16_t Pl[16*PLDS];
  int rt = blockIdx.x, bh = blockIdx.y;
  int b = bh / H_, h = bh % H_;
  int lane = threadIdx.x, lr = lane & 15, lkb = (lane >> 4) * 8;
  float sq = fq_scale(*sQkv);
  float s2 = sq * sq * 0.125f;
  float lmin = __uint_as_float(*lmin_slot);
  float sa = (1.0f / lmin) / 127.0f + 1e-8f;
  int qn = rt*16 + lr; if (qn > N_TOK-1) qn = N_TOK-1;
  long qoff = (long)(b*N_TOK + qn)*2304 + h*64 + lkb;
  f16x8 a0 = cvt_i8_f16(*(const i8x8*)&qkv8[qoff]);
  f16x8 a1 = cvt_i8_f16(*(const i8x8*)&qkv8[qoff + 32]);
  int rbase = (lane >> 4)*4;
  float pm[4], pinv[4];
  #pragma unroll
  for (int j = 0; j < 4; ++j){
    int r = rt*16 + rbase + j;
    pm[j] = marr[(long)bh*NP + r];
    pinv[j] = 1.0f / larr[(long)bh*NP + r];
  }
  for (int ct = 0; ct < NKP/16; ++ct){
    int kn = ct*16 + lr; int knc = kn > N_TOK-1 ? N_TOK-1 : kn;
    long koff = (long)(b*N_TOK + knc)*2304 + 768 + h*64 + lkb;
    f16x8 b0 = cvt_i8_f16(*(const i8x8*)&qkv8[koff]);
    f16x8 b1 = cvt_i8_f16(*(const i8x8*)&qkv8[koff + 32]);
    f32x4 sacc = {};
    sacc = MFMA_F16(a0, b0, sacc, 0, 0, 0);
    sacc = MFMA_F16(a1, b1, sacc, 0, 0, 0);
    bool cv = kn < N_TOK;
    #pragma unroll
    for (int j = 0; j < 4; ++j){
      int r = rt*16 + rbase + j;
      float p = 0.0f;
      if (cv && r < N_TOK) p = expf(sacc[j]*s2 - pm[j]) * pinv[j];
      float qp = fminf(rintf(p / sa), 127.0f);     // P >= 0
      Pl[(rbase + j)*PLDS + ct*16 + lr] = (f16_t)qp;
    }
  }
  __syncthreads();
  // PV: I[16 rows][64 d] = Pcodes[16][224] . Vcodes[224][64]  (exact integers)
  f32x4 acc[4] = {};
  for (int k0 = 0; k0 < NKP; k0 += 32){
    f16x8 a = *(const f16x8*)&Pl[lr*PLDS + k0 + lkb];
    #pragma unroll
    for (int nf = 0; nf < 4; ++nf){
      f16x8 bb = *(const f16x8*)&vt[((long)bh*DH + nf*16 + lr)*NKP + k0 + lkb];
      acc[nf] = MFMA_F16(a, bb, acc[nf], 0, 0, 0);
    }
  }
  #pragma unroll
  for (int j = 0; j < 4; ++j){
    int n = rt*16 + rbase + j;
    if (n < N_TOK){
      long orow = (long)(b*N_TOK + n)*C_ + h*DH;
      #pragma unroll
      for (int nf = 0; nf < 4; ++nf){
        float I  = acc[nf][j];                       // exact integer, |I| < 2^22
        float hi = rintf(I * (1.0f/2048.0f));
        float lo = (I - hi * 2048.0f) * (1.0f/2048.0f);  // |lo|<=0.5, f16-exact
        xa_hi[orow + nf*16 + lr] = (f16_t)hi;
        xa_lo[orow + nf*16 + lr] = (f16_t)lo;
      }
    }
  }
}

// ---------------- host ----------------
static inline int cdiv_i(long a, long b){ return (int)((a + b - 1) / b); }

extern "C" void kernel_launch(void* const* d_in, const int* in_sizes, int n_in,
                              void* d_out, int out_size, void* d_ws, size_t ws_size,
                              hipStream_t stream){
  const float* x      = (const float*)d_in[0];
  const float* w_qkv  = (const float*)d_in[1];
  const float* b_qkv  = (const float*)d_in[2];
  const float* w_proj = (const float*)d_in[3];
  const float* b_proj = (const float*)d_in[4];
  const float* w_fc1  = (const float*)d_in[5];
  const float* b_fc1  = (const float*)d_in[6];
  const float* w_fc2  = (const float*)d_in[7];
  const float* b_fc2  = (const float*)d_in[8];
  const float* g1     = (const float*)d_in[9];
  const float* be1    = (const float*)d_in[10];
  const float* g2     = (const float*)d_in[11];
  const float* be2    = (const float*)d_in[12];
  float* out = (float*)d_out;

  // ---- workspace (~115.2 MB) ----
  char* ws = (char*)d_ws;
  size_t off = 0;
  float* slots  = (float*)ws;              off += 1024;
  f16_t* wqkv_c = (f16_t*)(ws + off);      off += (size_t)2304*768*2;
  f16_t* wproj_c= (f16_t*)(ws + off);      off += (size_t)768*768*2;
  f16_t* wfc1_c = (f16_t*)(ws + off);      off += (size_t)3072*768*2;
  f16_t* wfc2_c = (f16_t*)(ws + off);      off += (size_t)768*3072*2;
  signed char* xn8 = (signed char*)(ws + off); off += (size_t)M_PAD*C_;
  char* r1 = ws + off;
  // attn phase
  signed char* qkv8 = (signed char*)r1;                                // 29.05 MB
  f16_t* vtb  = (f16_t*)(r1 + (size_t)M_VALID*2304);                   // 22.02 MB
  float* marr = (float*)(r1 + (size_t)M_VALID*2304 + (size_t)BH*DH*NKP*2);
  float* larr = marr + (size_t)BH*NP;
  size_t xa_off = (size_t)M_VALID*2304 + (size_t)BH*DH*NKP*2 + 2*(size_t)BH*NP*4;
  f16_t* xa_hi = (f16_t*)(r1 + xa_off);                                // 19.46 MB
  f16_t* xa_lo = (f16_t*)(r1 + xa_off + (size_t)M_PAD*C_*2);           // 19.46 MB
  size_t r1_sz = xa_off + 2*(size_t)M_PAD*C_*2;
  // mlp phase (overlays dead attn buffers; xa planes stay live through proj)
  float* x1 = (float*)r1;                                              // 38.73 MB
  signed char* h8 = (signed char*)(r1 + (size_t)M_VALID*C_*4);         // 38.93 MB
  off += r1_sz;
  const size_t NEED = off;

  if (ws_size < NEED){
    k_fill<<<256, 256, 0, stream>>>(out, out_size, 1.0e4f);  // sentinel
    return;
  }

  const long nW1 = (long)2304*768, nW2 = (long)768*768, nW3 = (long)3072*768, nW4 = (long)768*3072;
  const long nXC = (long)M_VALID*C_;
  const long nXC4 = nXC/4;
  float* raw = out;   // d_out doubles as f32 raw buffer

  k_init<<<1, 64, 0, stream>>>(slots);
  hipMemsetAsync(xn8 + (size_t)M_VALID*C_, 0, (size_t)(M_PAD - M_VALID)*C_, stream);
  hipMemsetAsync(xa_hi + (size_t)M_VALID*C_, 0, (size_t)(M_PAD - M_VALID)*C_*2, stream);
  hipMemsetAsync(xa_lo + (size_t)M_VALID*C_, 0, (size_t)(M_PAD - M_VALID)*C_*2, stream);

  // weight codes (amax: float4 grid-stride, capped grid, 1 atomic/block)
  k_amax<<<1024, 256, 0, stream>>>(w_qkv, nW1/4, &slots[S_WQKV]);
  k_amax<<<512, 256, 0, stream>>>(w_proj, nW2/4, &slots[S_WPROJ]);
  k_amax<<<1024, 256, 0, stream>>>(w_fc1, nW3/4, &slots[S_WFC1]);
  k_amax<<<1024, 256, 0, stream>>>(w_fc2, nW4/4, &slots[S_WFC2]);
  k_wcode<<<cdiv_i(nW1,256), 256, 0, stream>>>(w_qkv, wqkv_c, &slots[S_WQKV], nW1);
  k_wcode<<<cdiv_i(nW2,256), 256, 0, stream>>>(w_proj, wproj_c, &slots[S_WPROJ], nW2);
  k_wcode<<<cdiv_i(nW3,256), 256, 0, stream>>>(w_fc1, wfc1_c, &slots[S_WFC1], nW3);
  k_wcode<<<cdiv_i(nW4,256), 256, 0, stream>>>(w_fc2, wfc2_c, &slots[S_WFC2], nW4);

  // norm1 -> xn codes
  k_ln<false><<<M_VALID, 64, 0, stream>>>(x, g1, be1, nullptr, nullptr, &slots[S_LN1]);
  k_ln<true ><<<M_VALID, 64, 0, stream>>>(x, g1, be1, xn8, &slots[S_LN1], nullptr);

  // qkv: amax pass then code pass
  k_gemm<EPI_AMX><<<dim3(18, 99), 256, 0, stream>>>(xn8, wqkv_c, b_qkv,
      nullptr, nullptr, &slots[S_LN1], &slots[S_WQKV], nullptr, &slots[S_QKV], M_VALID, 2304, 768);
  k_gemm<EPI_CODE8><<<dim3(18, 99), 256, 0, stream>>>(xn8, wqkv_c, b_qkv,
      nullptr, qkv8, &slots[S_LN1], &slots[S_WQKV], &slots[S_QKV], nullptr, M_VALID, 2304, 768);

  // attention
  k_vtrans<<<BH, 64, 0, stream>>>(qkv8, vtb);
  k_attn1<<<dim3(NP/16, BH), 64, 0, stream>>>(qkv8, &slots[S_QKV], marr, larr,
      (unsigned int*)&slots[S_LMIN]);
  k_attn2pv<<<dim3(NP/16, BH), 64, 0, stream>>>(qkv8, vtb, &slots[S_QKV], marr, larr,
      (const unsigned int*)&slots[S_LMIN], xa_hi, xa_lo);

  // proj (exact I) -> raw(=out) + amax; residual1; fq -> x1
  k_gemmp<<<dim3(6, 99), 256, 0, stream>>>(xa_hi, xa_lo, wproj_c, b_proj, raw,
      (const unsigned int*)&slots[S_LMIN], &slots[S_QKV], &slots[S_WPROJ], &slots[S_PROJ],
      M_VALID, 768, 768);
  k_res<true><<<1040, 256, 0, stream>>>(raw, &slots[S_PROJ], x, &slots[S_R1], nXC4);
  k_fq_f32<<<2080, 256, 0, stream>>>(raw, x1, &slots[S_R1], nXC4);

  // norm2 -> xn codes
  k_ln<false><<<M_VALID, 64, 0, stream>>>(x1, g2, be2, nullptr, nullptr, &slots[S_LN2]);
  k_ln<true ><<<M_VALID, 64, 0, stream>>>(x1, g2, be2, xn8, &slots[S_LN2], nullptr);

  // fc1: gelu-amax pass then gelu-code pass
  k_gemm<EPI_GAMX><<<dim3(24, 99), 256, 0, stream>>>(xn8, wfc1_c, b_fc1,
      nullptr, nullptr, &slots[S_LN2], &slots[S_WFC1], nullptr, &slots[S_GELU], M_VALID, 3072, 768);
  k_gemm<EPI_GCODE8><<<dim3(24, 99), 256, 0, stream>>>(xn8, wfc1_c, b_fc1,
      nullptr, h8, &slots[S_LN2], &slots[S_WFC1], &slots[S_GELU], nullptr, M_VALID, 3072, 768);

  // fc2 -> raw(=out); residual2; final fq
  k_gemm<EPI_F32><<<dim3(6, 99), 256, 0, stream>>>(h8, wfc2_c, b_fc2,
      raw, nullptr, &slots[S_GELU], &slots[S_WFC2], nullptr, nullptr, M_VALID, 768, 3072);
  k_res<false><<<1040, 256, 0, stream>>>(raw, nullptr, x1, &slots[S_R2], nXC4);
  k_fq_f32<<<2080, 256, 0, stream>>>(raw, out, &slots[S_R2], nXC4);
}

// Round 9
// 1563.595 us; speedup vs baseline: 3.4523x; 1.0563x over previous
//
#include <hip/hip_runtime.h>
#include <hip/hip_bf16.h>
#include <math.h>

typedef _Float16 f16_t;
typedef _Float16 f16x8 __attribute__((ext_vector_type(8)));
typedef signed char i8x8 __attribute__((ext_vector_type(8)));
typedef float f32x4 __attribute__((ext_vector_type(4)));

#define MFMA_F16 __builtin_amdgcn_mfma_f32_16x16x32_f16

// ---- problem dims ----
#define B_      64
#define N_TOK   197
#define C_      768
#define H_      12
#define DH      64
#define DFF     3072
#define M_VALID (B_*N_TOK)   // 12608
#define M_PAD   12672        // 99*128
#define NP      208
#define NKP     224
#define BH      (B_*H_)      // 768
#define PLDS    232          // attn P LDS row stride (f16)
#define LS      40           // GEMM LDS row stride (f16): 80B -> 8-bank spread, 2-way free

// ---- scale slots ----
#define S_WQKV 0
#define S_WPROJ 1
#define S_WFC1 2
#define S_WFC2 3
#define S_LN1 4
#define S_QKV 5
#define S_LMIN 6
#define S_PROJ 7
#define S_R1 8
#define S_LN2 9
#define S_GELU 10
#define S_R2 11

// ---- GEMM epilogue modes ----
#define EPI_AMX    0  // amax |val| (no store)
#define EPI_CODE8  1  // fq -> i8 codes (valid rows)
#define EPI_VMAX   2  // max of val PRE-gelu (no store, no erff)
#define EPI_GCODE16 3 // gelu -> fq -> f16 codes, zero pads
#define EPI_F32    4  // store f32 val (valid rows)

// ---------------- helpers ----------------
__device__ __forceinline__ float wred_max(float v){
  #pragma unroll
  for (int o = 32; o; o >>= 1) v = fmaxf(v, __shfl_xor(v, o));
  return v;
}
__device__ __forceinline__ float wred_min(float v){
  #pragma unroll
  for (int o = 32; o; o >>= 1) v = fminf(v, __shfl_xor(v, o));
  return v;
}
__device__ __forceinline__ float wred_sum(float v){
  #pragma unroll
  for (int o = 32; o; o >>= 1) v += __shfl_xor(v, o);
  return v;
}
__device__ __forceinline__ void atomicMaxPosF(float* p, float v){
  atomicMax((int*)p, __float_as_int(v));  // valid for v >= 0
}
__device__ __forceinline__ void block_amax_commit(float m, float* slot){
  __shared__ float smx[4];
  int t = threadIdx.x, wave = t >> 6, lane = t & 63;
  m = wred_max(m);
  if (lane == 0) smx[wave] = m;
  __syncthreads();
  if (t == 0){
    float r = fmaxf(fmaxf(smx[0], smx[1]), fmaxf(smx[2], smx[3]));
    atomicMaxPosF(slot, r);
  }
}
__device__ __forceinline__ float fq_scale(float amax){ return amax / 127.0f + 1e-8f; }
__device__ __forceinline__ float fq_q(float x, float s){
  return fminf(fmaxf(rintf(x / s), -128.0f), 127.0f);
}
__device__ __forceinline__ float fq_apply(float x, float s){ return fq_q(x, s) * s; }
__device__ __forceinline__ float gelu_f(float v){
  return 0.5f * v * (1.0f + erff(v * 0.70710678118654752440f));
}
__device__ __forceinline__ f16x8 cvt_i8_f16(i8x8 v){
  f16x8 r;
  #pragma unroll
  for (int i = 0; i < 8; ++i) r[i] = (_Float16)(short)v[i];
  return r;
}

// ---------------- small kernels ----------------
__global__ void k_init(float* slots){
  int i = threadIdx.x;
  if (i < 32) slots[i] = 0.0f;
  if (i == S_LMIN) ((unsigned int*)slots)[i] = 0x7F800000u;  // +inf
}

__global__ void k_fill(float* p, long n, float val){
  long i = (long)blockIdx.x * blockDim.x + threadIdx.x;
  long st = (long)gridDim.x * blockDim.x;
  for (; i < n; i += st) p[i] = val;
}

// slot: vmax(pre-gelu) -> amax(gelu). gelu monotone above its min (-0.16997@-0.752);
// 39M samples densely cover the dip, so max|gelu| = max(gelu(vmax), 0.16997).
__global__ void k_gelu_amax(float* slot){
  if (threadIdx.x == 0) *slot = fmaxf(gelu_f(*slot), 0.16997120f);
}

__global__ __launch_bounds__(256) void k_amax(const float* __restrict__ p, long n4, float* slot){
  long i = (long)blockIdx.x * blockDim.x + threadIdx.x;
  long st = (long)gridDim.x * blockDim.x;
  const f32x4* p4 = (const f32x4*)p;
  float m = 0.0f;
  for (; i < n4; i += st){
    f32x4 v = p4[i];
    m = fmaxf(m, fmaxf(fmaxf(fabsf(v[0]), fabsf(v[1])), fmaxf(fabsf(v[2]), fabsf(v[3]))));
  }
  block_amax_commit(m, slot);
}

__global__ void k_wcode(const float* __restrict__ in, f16_t* __restrict__ out,
                        const float* amax, long n){
  float s = fq_scale(*amax);
  long i = (long)blockIdx.x * blockDim.x + threadIdx.x;
  long st = (long)gridDim.x * blockDim.x;
  for (; i < n; i += st) out[i] = (f16_t)fq_q(in[i], s);
}

__global__ __launch_bounds__(256) void k_fq_f32(const float* __restrict__ in,
    float* __restrict__ out, const float* amax, long n4){
  float s = fq_scale(*amax);
  long i = (long)blockIdx.x * blockDim.x + threadIdx.x;
  long st = (long)gridDim.x * blockDim.x;
  const f32x4* in4 = (const f32x4*)in;
  f32x4* out4 = (f32x4*)out;
  for (; i < n4; i += st){
    f32x4 v = in4[i];
    #pragma unroll
    for (int e = 0; e < 4; ++e) v[e] = fq_apply(v[e], s);
    out4[i] = v;
  }
}

// LayerNorm: pass1 amax; pass2 store f16 codes
template<bool STORE>
__global__ __launch_bounds__(64) void k_ln(const float* __restrict__ x,
    const float* __restrict__ g, const float* __restrict__ b,
    f16_t* __restrict__ y16, const float* scale_slot, float* amax_slot){
  int row = blockIdx.x, lane = threadIdx.x;
  const float* xr = x + (long)row * C_;
  float v[12]; float s = 0.0f;
  #pragma unroll
  for (int i = 0; i < 12; ++i){ v[i] = xr[lane + 64*i]; s += v[i]; }
  s = wred_sum(s);
  float mean = s / 768.0f;
  float q = 0.0f;
  #pragma unroll
  for (int i = 0; i < 12; ++i){ float d = v[i] - mean; q += d*d; }
  q = wred_sum(q);
  float inv = rsqrtf(q / 768.0f + 1e-6f);
  if (STORE){
    float fs = fq_scale(*scale_slot);
    f16_t* yr = y16 + (long)row * C_;
    #pragma unroll
    for (int i = 0; i < 12; ++i){
      int c = lane + 64*i;
      float o = (v[i] - mean) * inv * g[c] + b[c];
      yr[c] = (f16_t)fq_q(o, fs);
    }
  } else {
    float mx = 0.0f;
    #pragma unroll
    for (int i = 0; i < 12; ++i){
      int c = lane + 64*i;
      float o = (v[i] - mean) * inv * g[c] + b[c];
      mx = fmaxf(mx, fabsf(o));
    }
    mx = wred_max(mx);
    if (lane == 0) atomicMaxPosF(amax_slot, mx);
  }
}

template<bool FQRAW>
__global__ __launch_bounds__(256) void k_res(float* __restrict__ raw, const float* amax_raw,
                      const float* __restrict__ xin, float* amax_out, long n4){
  float s = 0.0f;
  if (FQRAW) s = fq_scale(*amax_raw);
  long i = (long)blockIdx.x * blockDim.x + threadIdx.x;
  long st = (long)gridDim.x * blockDim.x;
  f32x4* raw4 = (f32x4*)raw;
  const f32x4* xin4 = (const f32x4*)xin;
  float mx = 0.0f;
  for (; i < n4; i += st){
    f32x4 v = raw4[i];
    f32x4 xv = xin4[i];
    #pragma unroll
    for (int e = 0; e < 4; ++e){
      float t = FQRAW ? fq_apply(v[e], s) : v[e];
      float r = xv[e] + t;
      v[e] = r;
      mx = fmaxf(mx, fabsf(r));
    }
    raw4[i] = v;
  }
  block_amax_commit(mx, amax_out);
}

// ---------------- code GEMM: val = (A16 codes . W codes)*sA*sW + bias ----------------
// A16: f16 codes [Mpad][K]; W: f16 codes [N][K]; 128x128 tile, 4 waves, BK=32, LDS stride 40
template<int EPI>
__global__ __launch_bounds__(256) void k_gemm(const f16_t* __restrict__ A16,
    const f16_t* __restrict__ W, const float* __restrict__ bias,
    float* __restrict__ Cf, signed char* __restrict__ C8, f16_t* __restrict__ C16,
    const float* __restrict__ sA, const float* __restrict__ sW,
    const float* __restrict__ sOut, float* __restrict__ amax_slot,
    int Mv, int N, int K){
  __shared__ __align__(16) f16_t As[128*LS];
  __shared__ __align__(16) f16_t Ws[128*LS];
  const int bm = blockIdx.y * 128, bn = blockIdx.x * 128;
  const int t = threadIdx.x;
  const int lane = t & 63;
  const int wave = t >> 6;
  const int wr = (wave >> 1) * 64, wc = (wave & 1) * 64;
  const int lr = lane & 15, lkb = (lane >> 4) * 8;
  f32x4 acc[4][4] = {};
  for (int k0 = 0; k0 < K; k0 += 32){
    __syncthreads();
    #pragma unroll
    for (int n = 0; n < 2; ++n){
      int p = t*8 + n*2048;
      int r = p >> 5, c = p & 31;
      *(f16x8*)&As[r*LS + c] = *(const f16x8*)&A16[(long)(bm + r)*K + k0 + c];
      *(f16x8*)&Ws[r*LS + c] = *(const f16x8*)&W[(long)(bn + r)*K + k0 + c];
    }
    __syncthreads();
    f16x8 af[4], wf[4];
    #pragma unroll
    for (int i = 0; i < 4; ++i){
      af[i] = *(const f16x8*)&As[(wr + i*16 + lr)*LS + lkb];
      wf[i] = *(const f16x8*)&Ws[(wc + i*16 + lr)*LS + lkb];
    }
    #pragma unroll
    for (int mf = 0; mf < 4; ++mf)
      #pragma unroll
      for (int nf = 0; nf < 4; ++nf)
        acc[mf][nf] = MFMA_F16(af[mf], wf[nf], acc[mf][nf], 0, 0, 0);
  }
  const float sc = fq_scale(*sA) * fq_scale(*sW);
  float fs = 0.0f;
  if (EPI == EPI_CODE8 || EPI == EPI_GCODE16) fs = fq_scale(*sOut);
  float mx = 0.0f;
  const int rl = (lane >> 4) * 4;
  #pragma unroll
  for (int mf = 0; mf < 4; ++mf){
    #pragma unroll
    for (int j = 0; j < 4; ++j){
      int row = bm + wr + mf*16 + rl + j;
      bool valid = row < Mv;
      #pragma unroll
      for (int nf = 0; nf < 4; ++nf){
        int col = bn + wc + nf*16 + lr;
        float v = acc[mf][nf][j] * sc + bias[col];
        if (EPI == EPI_AMX){
          if (valid) mx = fmaxf(mx, fabsf(v));
        } else if (EPI == EPI_VMAX){
          if (valid) mx = fmaxf(mx, v);          // pre-gelu signed max; no erff here
        } else if (EPI == EPI_CODE8){
          if (valid) C8[(long)row*N + col] = (signed char)(int)fq_q(v, fs);
        } else if (EPI == EPI_GCODE16){
          float o = valid ? fq_q(gelu_f(v), fs) : 0.0f;
          C16[(long)row*N + col] = (f16_t)o;     // zero pads for fc2
        } else if (EPI == EPI_F32){
          if (valid) Cf[(long)row*N + col] = v;
        }
      }
    }
  }
  if (EPI == EPI_AMX || EPI == EPI_VMAX){
    mx = wred_max(mx);
    if (lane == 0) atomicMaxPosF(amax_slot, mx);
  }
}

// ---------------- proj GEMM: A = exact integer I via hi/lo f16 planes ----------------
__global__ __launch_bounds__(256) void k_gemmp(const f16_t* __restrict__ Ahi,
    const f16_t* __restrict__ Alo, const f16_t* __restrict__ W,
    const float* __restrict__ bias, float* __restrict__ Cf,
    const unsigned int* __restrict__ lmin_slot, const float* __restrict__ sQkv,
    const float* __restrict__ sW, float* __restrict__ amax_slot,
    int Mv, int N, int K){
  __shared__ __align__(16) f16_t Ah[128*LS];
  __shared__ __align__(16) f16_t Al[128*LS];
  __shared__ __align__(16) f16_t Ws[128*LS];
  const int bm = blockIdx.y * 128, bn = blockIdx.x * 128;
  const int t = threadIdx.x;
  const int lane = t & 63;
  const int wave = t >> 6;
  const int wr = (wave >> 1) * 64, wc = (wave & 1) * 64;
  const int lr = lane & 15, lkb = (lane >> 4) * 8;
  f32x4 acc[4][4] = {};
  for (int k0 = 0; k0 < K; k0 += 32){
    __syncthreads();
    #pragma unroll
    for (int n = 0; n < 2; ++n){
      int p = t*8 + n*2048;
      int r = p >> 5, c = p & 31;
      *(f16x8*)&Ah[r*LS + c] = *(const f16x8*)&Ahi[(long)(bm + r)*K + k0 + c];
      *(f16x8*)&Al[r*LS + c] = *(const f16x8*)&Alo[(long)(bm + r)*K + k0 + c];
      *(f16x8*)&Ws[r*LS + c] = *(const f16x8*)&W[(long)(bn + r)*K + k0 + c];
    }
    __syncthreads();
    f16x8 ah[4], al[4], wf[4];
    #pragma unroll
    for (int i = 0; i < 4; ++i){
      ah[i] = *(const f16x8*)&Ah[(wr + i*16 + lr)*LS + lkb];
      al[i] = *(const f16x8*)&Al[(wr + i*16 + lr)*LS + lkb];
      wf[i] = *(const f16x8*)&Ws[(wc + i*16 + lr)*LS + lkb];
    }
    #pragma unroll
    for (int mf = 0; mf < 4; ++mf)
      #pragma unroll
      for (int nf = 0; nf < 4; ++nf){
        acc[mf][nf] = MFMA_F16(ah[mf], wf[nf], acc[mf][nf], 0, 0, 0);
        acc[mf][nf] = MFMA_F16(al[mf], wf[nf], acc[mf][nf], 0, 0, 0);
      }
  }
  float sa_p = (1.0f / __uint_as_float(*lmin_slot)) / 127.0f + 1e-8f;
  const float cs = sa_p * fq_scale(*sQkv) * fq_scale(*sW) * 2048.0f;
  float mx = 0.0f;
  const int rl = (lane >> 4) * 4;
  #pragma unroll
  for (int mf = 0; mf < 4; ++mf){
    #pragma unroll
    for (int j = 0; j < 4; ++j){
      int row = bm + wr + mf*16 + rl + j;
      if (row < Mv){
        #pragma unroll
        for (int nf = 0; nf < 4; ++nf){
          int col = bn + wc + nf*16 + lr;
          float v = acc[mf][nf][j] * cs + bias[col];
          Cf[(long)row*N + col] = v;
          mx = fmaxf(mx, fabsf(v));
        }
      }
    }
  }
  mx = wred_max(mx);
  if (lane == 0) atomicMaxPosF(amax_slot, mx);
}

// ---------------- V transpose ----------------
__global__ __launch_bounds__(64) void k_vtrans(const signed char* __restrict__ qkv8,
                                               f16_t* __restrict__ vt){
  int bh = blockIdx.x; int b = bh / H_, h = bh % H_, d = threadIdx.x;
  long coff = 1536 + h*64 + d;
  for (int m8 = 0; m8 < NKP/8; ++m8){
    f16_t vv[8];
    #pragma unroll
    for (int e = 0; e < 8; ++e){
      int m = m8*8 + e;
      signed char code = (m < N_TOK) ? qkv8[(long)(b*N_TOK + m)*2304 + coff] : (signed char)0;
      vv[e] = (f16_t)(short)code;
    }
    *(f16x8*)&vt[((long)bh*DH + d)*NKP + m8*8] = *(f16x8*)vv;
  }
}

// ---------------- attention pass1 ----------------
__global__ __launch_bounds__(64) void k_attn1(const signed char* __restrict__ qkv8,
    const float* __restrict__ sQkv, float* __restrict__ marr,
    float* __restrict__ larr, unsigned int* lmin_slot){
  int rt = blockIdx.x, bh = blockIdx.y;
  int b = bh / H_, h = bh % H_;
  int lane = threadIdx.x, lr = lane & 15, lkb = (lane >> 4) * 8;
  float sq = fq_scale(*sQkv);
  float s2 = sq * sq * 0.125f;
  int qn = rt*16 + lr; if (qn > N_TOK-1) qn = N_TOK-1;
  long qoff = (long)(b*N_TOK + qn)*2304 + h*64 + lkb;
  f16x8 a0 = cvt_i8_f16(*(const i8x8*)&qkv8[qoff]);
  f16x8 a1 = cvt_i8_f16(*(const i8x8*)&qkv8[qoff + 32]);
  float m[4], l[4];
  #pragma unroll
  for (int j = 0; j < 4; ++j){ m[j] = -1e30f; l[j] = 0.0f; }
  for (int ct = 0; ct < NKP/16; ++ct){
    int kn = ct*16 + lr; int knc = kn > N_TOK-1 ? N_TOK-1 : kn;
    long koff = (long)(b*N_TOK + knc)*2304 + 768 + h*64 + lkb;
    f16x8 b0 = cvt_i8_f16(*(const i8x8*)&qkv8[koff]);
    f16x8 b1 = cvt_i8_f16(*(const i8x8*)&qkv8[koff + 32]);
    f32x4 sacc = {};
    sacc = MFMA_F16(a0, b0, sacc, 0, 0, 0);
    sacc = MFMA_F16(a1, b1, sacc, 0, 0, 0);
    bool cv = kn < N_TOK;
    #pragma unroll
    for (int j = 0; j < 4; ++j){
      float sv = cv ? sacc[j]*s2 : -1e30f;
      float mn = fmaxf(m[j], sv);
      l[j] = l[j]*expf(m[j]-mn) + expf(sv-mn);
      m[j] = mn;
    }
  }
  #pragma unroll
  for (int mask = 1; mask < 16; mask <<= 1){
    #pragma unroll
    for (int j = 0; j < 4; ++j){
      float mo = __shfl_xor(m[j], mask);
      float lo = __shfl_xor(l[j], mask);
      float mn = fmaxf(m[j], mo);
      l[j] = l[j]*expf(m[j]-mn) + lo*expf(mo-mn);
      m[j] = mn;
    }
  }
  float lmn = 3.4e38f;
  #pragma unroll
  for (int j = 0; j < 4; ++j){
    int r = rt*16 + (lane >> 4)*4 + j;
    if (r < N_TOK) lmn = fminf(lmn, l[j]);
    if (lr == 0 && r < NP){ marr[(long)bh*NP + r] = m[j]; larr[(long)bh*NP + r] = l[j]; }
  }
  lmn = wred_min(lmn);
  if (lane == 0) atomicMin(lmin_slot, __float_as_uint(lmn));
}

// ---------------- attention pass2 + PV ----------------
__global__ __launch_bounds__(64) void k_attn2pv(const signed char* __restrict__ qkv8,
    const f16_t* __restrict__ vt, const float* __restrict__ sQkv,
    const float* __restrict__ marr, const float* __restrict__ larr,
    const unsigned int* lmin_slot, f16_t* __restrict__ xa_hi, f16_t* __restrict__ xa_lo){
  __shared__ __align__(16) f16_t Pl[16*PLDS];
  int rt = blockIdx.x, bh = blockIdx.y;
  int b = bh / H_, h = bh % H_;
  int lane = threadIdx.x, lr = lane & 15, lkb = (lane >> 4) * 8;
  float sq = fq_scale(*sQkv);
  float s2 = sq * sq * 0.125f;
  float lmin = __uint_as_float(*lmin_slot);
  float sa = (1.0f / lmin) / 127.0f + 1e-8f;
  int qn = rt*16 + lr; if (qn > N_TOK-1) qn = N_TOK-1;
  long qoff = (long)(b*N_TOK + qn)*2304 + h*64 + lkb;
  f16x8 a0 = cvt_i8_f16(*(const i8x8*)&qkv8[qoff]);
  f16x8 a1 = cvt_i8_f16(*(const i8x8*)&qkv8[qoff + 32]);
  int rbase = (lane >> 4)*4;
  float pm[4], pinv[4];
  #pragma unroll
  for (int j = 0; j < 4; ++j){
    int r = rt*16 + rbase + j;
    pm[j] = marr[(long)bh*NP + r];
    pinv[j] = 1.0f / larr[(long)bh*NP + r];
  }
  for (int ct = 0; ct < NKP/16; ++ct){
    int kn = ct*16 + lr; int knc = kn > N_TOK-1 ? N_TOK-1 : kn;
    long koff = (long)(b*N_TOK + knc)*2304 + 768 + h*64 + lkb;
    f16x8 b0 = cvt_i8_f16(*(const i8x8*)&qkv8[koff]);
    f16x8 b1 = cvt_i8_f16(*(const i8x8*)&qkv8[koff + 32]);
    f32x4 sacc = {};
    sacc = MFMA_F16(a0, b0, sacc, 0, 0, 0);
    sacc = MFMA_F16(a1, b1, sacc, 0, 0, 0);
    bool cv = kn < N_TOK;
    #pragma unroll
    for (int j = 0; j < 4; ++j){
      int r = rt*16 + rbase + j;
      float p = 0.0f;
      if (cv && r < N_TOK) p = expf(sacc[j]*s2 - pm[j]) * pinv[j];
      float qp = fminf(rintf(p / sa), 127.0f);
      Pl[(rbase + j)*PLDS + ct*16 + lr] = (f16_t)qp;
    }
  }
  __syncthreads();
  f32x4 acc[4] = {};
  for (int k0 = 0; k0 < NKP; k0 += 32){
    f16x8 a = *(const f16x8*)&Pl[lr*PLDS + k0 + lkb];
    #pragma unroll
    for (int nf = 0; nf < 4; ++nf){
      f16x8 bb = *(const f16x8*)&vt[((long)bh*DH + nf*16 + lr)*NKP + k0 + lkb];
      acc[nf] = MFMA_F16(a, bb, acc[nf], 0, 0, 0);
    }
  }
  #pragma unroll
  for (int j = 0; j < 4; ++j){
    int n = rt*16 + rbase + j;
    if (n < N_TOK){
      long orow = (long)(b*N_TOK + n)*C_ + h*DH;
      #pragma unroll
      for (int nf = 0; nf < 4; ++nf){
        float I  = acc[nf][j];
        float hi = rintf(I * (1.0f/2048.0f));
        float lo = (I - hi * 2048.0f) * (1.0f/2048.0f);
        xa_hi[orow + nf*16 + lr] = (f16_t)hi;
        xa_lo[orow + nf*16 + lr] = (f16_t)lo;
      }
    }
  }
}

// ---------------- host ----------------
static inline int cdiv_i(long a, long b){ return (int)((a + b - 1) / b); }

extern "C" void kernel_launch(void* const* d_in, const int* in_sizes, int n_in,
                              void* d_out, int out_size, void* d_ws, size_t ws_size,
                              hipStream_t stream){
  const float* x      = (const float*)d_in[0];
  const float* w_qkv  = (const float*)d_in[1];
  const float* b_qkv  = (const float*)d_in[2];
  const float* w_proj = (const float*)d_in[3];
  const float* b_proj = (const float*)d_in[4];
  const float* w_fc1  = (const float*)d_in[5];
  const float* b_fc1  = (const float*)d_in[6];
  const float* w_fc2  = (const float*)d_in[7];
  const float* b_fc2  = (const float*)d_in[8];
  const float* g1     = (const float*)d_in[9];
  const float* be1    = (const float*)d_in[10];
  const float* g2     = (const float*)d_in[11];
  const float* be2    = (const float*)d_in[12];
  float* out = (float*)d_out;

  // ---- workspace (150,209,536 B == round-5-proven footprint) ----
  char* ws = (char*)d_ws;
  size_t off = 0;
  float* slots  = (float*)ws;              off += 1024;
  f16_t* wqkv_c = (f16_t*)(ws + off);      off += (size_t)2304*768*2;
  f16_t* wproj_c= (f16_t*)(ws + off);      off += (size_t)768*768*2;
  f16_t* wfc1_c = (f16_t*)(ws + off);      off += (size_t)3072*768*2;
  f16_t* wfc2_c = (f16_t*)(ws + off);      off += (size_t)768*3072*2;
  f16_t* xn16   = (f16_t*)(ws + off);      off += (size_t)M_PAD*C_*2;   // LN codes f16
  char* r1 = ws + off;
  // attn phase
  signed char* qkv8 = (signed char*)r1;                                // 29.05 MB
  f16_t* vtb  = (f16_t*)(r1 + (size_t)M_VALID*2304);                   // 22.02 MB
  float* marr = (float*)(r1 + (size_t)M_VALID*2304 + (size_t)BH*DH*NKP*2);
  float* larr = marr + (size_t)BH*NP;
  size_t xa_off = (size_t)M_VALID*2304 + (size_t)BH*DH*NKP*2 + 2*(size_t)BH*NP*4;
  f16_t* xa_hi = (f16_t*)(r1 + xa_off);
  f16_t* xa_lo = (f16_t*)(r1 + xa_off + (size_t)M_PAD*C_*2);
  size_t attn_sz = xa_off + 2*(size_t)M_PAD*C_*2;                      // 91.3 MB
  // mlp phase (overlays dead attn buffers)
  float* x1 = (float*)r1;                                              // 38.73 MB
  f16_t* h16 = (f16_t*)(r1 + (size_t)M_VALID*C_*4);                    // 77.86 MB
  size_t mlp_sz = (size_t)M_VALID*C_*4 + (size_t)M_PAD*DFF*2;          // 116.6 MB
  off += (attn_sz > mlp_sz ? attn_sz : mlp_sz);
  const size_t NEED = off;

  if (ws_size < NEED){
    k_fill<<<256, 256, 0, stream>>>(out, out_size, 1.0e4f);  // sentinel
    return;
  }

  const long nW1 = (long)2304*768, nW2 = (long)768*768, nW3 = (long)3072*768, nW4 = (long)768*3072;
  const long nXC = (long)M_VALID*C_;
  const long nXC4 = nXC/4;
  float* raw = out;   // d_out doubles as f32 raw buffer

  k_init<<<1, 64, 0, stream>>>(slots);
  hipMemsetAsync(xn16 + (size_t)M_VALID*C_, 0, (size_t)(M_PAD - M_VALID)*C_*2, stream);
  hipMemsetAsync(xa_hi + (size_t)M_VALID*C_, 0, (size_t)(M_PAD - M_VALID)*C_*2, stream);
  hipMemsetAsync(xa_lo + (size_t)M_VALID*C_, 0, (size_t)(M_PAD - M_VALID)*C_*2, stream);

  // weight codes
  k_amax<<<1024, 256, 0, stream>>>(w_qkv, nW1/4, &slots[S_WQKV]);
  k_amax<<<512, 256, 0, stream>>>(w_proj, nW2/4, &slots[S_WPROJ]);
  k_amax<<<1024, 256, 0, stream>>>(w_fc1, nW3/4, &slots[S_WFC1]);
  k_amax<<<1024, 256, 0, stream>>>(w_fc2, nW4/4, &slots[S_WFC2]);
  k_wcode<<<cdiv_i(nW1,256), 256, 0, stream>>>(w_qkv, wqkv_c, &slots[S_WQKV], nW1);
  k_wcode<<<cdiv_i(nW2,256), 256, 0, stream>>>(w_proj, wproj_c, &slots[S_WPROJ], nW2);
  k_wcode<<<cdiv_i(nW3,256), 256, 0, stream>>>(w_fc1, wfc1_c, &slots[S_WFC1], nW3);
  k_wcode<<<cdiv_i(nW4,256), 256, 0, stream>>>(w_fc2, wfc2_c, &slots[S_WFC2], nW4);

  // norm1 -> xn16 codes
  k_ln<false><<<M_VALID, 64, 0, stream>>>(x, g1, be1, nullptr, nullptr, &slots[S_LN1]);
  k_ln<true ><<<M_VALID, 64, 0, stream>>>(x, g1, be1, xn16, &slots[S_LN1], nullptr);

  // qkv: amax pass then code pass (i8 out for attention)
  k_gemm<EPI_AMX><<<dim3(18, 99), 256, 0, stream>>>(xn16, wqkv_c, b_qkv,
      nullptr, nullptr, nullptr, &slots[S_LN1], &slots[S_WQKV], nullptr, &slots[S_QKV], M_VALID, 2304, 768);
  k_gemm<EPI_CODE8><<<dim3(18, 99), 256, 0, stream>>>(xn16, wqkv_c, b_qkv,
      nullptr, qkv8, nullptr, &slots[S_LN1], &slots[S_WQKV], &slots[S_QKV], nullptr, M_VALID, 2304, 768);

  // attention
  k_vtrans<<<BH, 64, 0, stream>>>(qkv8, vtb);
  k_attn1<<<dim3(NP/16, BH), 64, 0, stream>>>(qkv8, &slots[S_QKV], marr, larr,
      (unsigned int*)&slots[S_LMIN]);
  k_attn2pv<<<dim3(NP/16, BH), 64, 0, stream>>>(qkv8, vtb, &slots[S_QKV], marr, larr,
      (const unsigned int*)&slots[S_LMIN], xa_hi, xa_lo);

  // proj (exact I) -> raw(=out) + amax; residual1; fq -> x1
  k_gemmp<<<dim3(6, 99), 256, 0, stream>>>(xa_hi, xa_lo, wproj_c, b_proj, raw,
      (const unsigned int*)&slots[S_LMIN], &slots[S_QKV], &slots[S_WPROJ], &slots[S_PROJ],
      M_VALID, 768, 768);
  k_res<true><<<1040, 256, 0, stream>>>(raw, &slots[S_PROJ], x, &slots[S_R1], nXC4);
  k_fq_f32<<<2080, 256, 0, stream>>>(raw, x1, &slots[S_R1], nXC4);

  // norm2 -> xn16 codes
  k_ln<false><<<M_VALID, 64, 0, stream>>>(x1, g2, be2, nullptr, nullptr, &slots[S_LN2]);
  k_ln<true ><<<M_VALID, 64, 0, stream>>>(x1, g2, be2, xn16, &slots[S_LN2], nullptr);

  // fc1: vmax pass (no erff), slot -> gelu amax, then gelu-code pass -> h16
  k_gemm<EPI_VMAX><<<dim3(24, 99), 256, 0, stream>>>(xn16, wfc1_c, b_fc1,
      nullptr, nullptr, nullptr, &slots[S_LN2], &slots[S_WFC1], nullptr, &slots[S_GELU], M_VALID, 3072, 768);
  k_gelu_amax<<<1, 1, 0, stream>>>(&slots[S_GELU]);
  k_gemm<EPI_GCODE16><<<dim3(24, 99), 256, 0, stream>>>(xn16, wfc1_c, b_fc1,
      nullptr, nullptr, h16, &slots[S_LN2], &slots[S_WFC1], &slots[S_GELU], nullptr, M_VALID, 3072, 768);

  // fc2 -> raw(=out); residual2; final fq
  k_gemm<EPI_F32><<<dim3(6, 99), 256, 0, stream>>>(h16, wfc2_c, b_fc2,
      raw, nullptr, nullptr, &slots[S_GELU], &slots[S_WFC2], nullptr, nullptr, M_VALID, 768, 3072);
  k_res<false><<<1040, 256, 0, stream>>>(raw, nullptr, x1, &slots[S_R2], nXC4);
  k_fq_f32<<<2080, 256, 0, stream>>>(raw, out, &slots[S_R2], nXC4);
}

// Round 10
// 1556.985 us; speedup vs baseline: 3.4669x; 1.0042x over previous
//
#include <hip/hip_runtime.h>
#include <hip/hip_bf16.h>
#include <math.h>

typedef _Float16 f16_t;
typedef _Float16 f16x8 __attribute__((ext_vector_type(8)));
typedef signed char i8x8 __attribute__((ext_vector_type(8)));
typedef float f32x4 __attribute__((ext_vector_type(4)));

#define MFMA_F16 __builtin_amdgcn_mfma_f32_16x16x32_f16

// ---- problem dims ----
#define B_      64
#define N_TOK   197
#define C_      768
#define H_      12
#define DH      64
#define DFF     3072
#define M_VALID (B_*N_TOK)   // 12608
#define M_PAD   12672        // 99*128
#define NP      208
#define NKP     224
#define BH      (B_*H_)      // 768
#define PLDS    232          // attn P LDS row stride (f16)
#define LS      32           // GEMM LDS row stride (f16) — linear, required by global_load_lds

// ---- scale slots ----
#define S_WQKV 0
#define S_WPROJ 1
#define S_WFC1 2
#define S_WFC2 3
#define S_LN1 4
#define S_QKV 5
#define S_LMIN 6
#define S_PROJ 7
#define S_R1 8
#define S_LN2 9
#define S_GELU 10
#define S_R2 11

// ---- GEMM epilogue modes ----
#define EPI_AMX    0  // amax |val| (no store)
#define EPI_CODE8  1  // fq -> i8 codes (valid rows)
#define EPI_VMAX   2  // max of val PRE-gelu (no store, no erff)
#define EPI_GCODE16 3 // gelu -> fq -> f16 codes, zero pads
#define EPI_F32    4  // store f32 val (valid rows)

// ---------------- helpers ----------------
__device__ __forceinline__ float wred_max(float v){
  #pragma unroll
  for (int o = 32; o; o >>= 1) v = fmaxf(v, __shfl_xor(v, o));
  return v;
}
__device__ __forceinline__ float wred_min(float v){
  #pragma unroll
  for (int o = 32; o; o >>= 1) v = fminf(v, __shfl_xor(v, o));
  return v;
}
__device__ __forceinline__ float wred_sum(float v){
  #pragma unroll
  for (int o = 32; o; o >>= 1) v += __shfl_xor(v, o);
  return v;
}
__device__ __forceinline__ void atomicMaxPosF(float* p, float v){
  atomicMax((int*)p, __float_as_int(v));  // valid for v >= 0
}
__device__ __forceinline__ void block_amax_commit(float m, float* slot){
  __shared__ float smx[4];
  int t = threadIdx.x, wave = t >> 6, lane = t & 63;
  m = wred_max(m);
  if (lane == 0) smx[wave] = m;
  __syncthreads();
  if (t == 0){
    float r = fmaxf(fmaxf(smx[0], smx[1]), fmaxf(smx[2], smx[3]));
    atomicMaxPosF(slot, r);
  }
}
__device__ __forceinline__ float fq_scale(float amax){ return amax / 127.0f + 1e-8f; }
__device__ __forceinline__ float fq_q(float x, float s){
  return fminf(fmaxf(rintf(x / s), -128.0f), 127.0f);
}
__device__ __forceinline__ float fq_apply(float x, float s){ return fq_q(x, s) * s; }
__device__ __forceinline__ float gelu_f(float v){
  return 0.5f * v * (1.0f + erff(v * 0.70710678118654752440f));
}
__device__ __forceinline__ f16x8 cvt_i8_f16(i8x8 v){
  f16x8 r;
  #pragma unroll
  for (int i = 0; i < 8; ++i) r[i] = (_Float16)(short)v[i];
  return r;
}
// async global->LDS, 16B/lane; LDS dest = wave-uniform base + lane*16 (m97/m104)
__device__ __forceinline__ void gload16(const void* g, void* l){
  __builtin_amdgcn_global_load_lds((const __attribute__((address_space(1))) void*)g,
                                   (__attribute__((address_space(3))) void*)l, 16, 0, 0);
}

// ---------------- small kernels ----------------
__global__ void k_init(float* slots){
  int i = threadIdx.x;
  if (i < 32) slots[i] = 0.0f;
  if (i == S_LMIN) ((unsigned int*)slots)[i] = 0x7F800000u;  // +inf
}

__global__ void k_fill(float* p, long n, float val){
  long i = (long)blockIdx.x * blockDim.x + threadIdx.x;
  long st = (long)gridDim.x * blockDim.x;
  for (; i < n; i += st) p[i] = val;
}

// slot: vmax(pre-gelu) -> amax(gelu). gelu monotone above its min (-0.16997@-0.752).
__global__ void k_gelu_amax(float* slot){
  if (threadIdx.x == 0) *slot = fmaxf(gelu_f(*slot), 0.16997120f);
}

__global__ __launch_bounds__(256) void k_amax(const float* __restrict__ p, long n4, float* slot){
  long i = (long)blockIdx.x * blockDim.x + threadIdx.x;
  long st = (long)gridDim.x * blockDim.x;
  const f32x4* p4 = (const f32x4*)p;
  float m = 0.0f;
  for (; i < n4; i += st){
    f32x4 v = p4[i];
    m = fmaxf(m, fmaxf(fmaxf(fabsf(v[0]), fabsf(v[1])), fmaxf(fabsf(v[2]), fabsf(v[3]))));
  }
  block_amax_commit(m, slot);
}

__global__ void k_wcode(const float* __restrict__ in, f16_t* __restrict__ out,
                        const float* amax, long n){
  float s = fq_scale(*amax);
  long i = (long)blockIdx.x * blockDim.x + threadIdx.x;
  long st = (long)gridDim.x * blockDim.x;
  for (; i < n; i += st) out[i] = (f16_t)fq_q(in[i], s);
}

__global__ __launch_bounds__(256) void k_fq_f32(const float* __restrict__ in,
    float* __restrict__ out, const float* amax, long n4){
  float s = fq_scale(*amax);
  long i = (long)blockIdx.x * blockDim.x + threadIdx.x;
  long st = (long)gridDim.x * blockDim.x;
  const f32x4* in4 = (const f32x4*)in;
  f32x4* out4 = (f32x4*)out;
  for (; i < n4; i += st){
    f32x4 v = in4[i];
    #pragma unroll
    for (int e = 0; e < 4; ++e) v[e] = fq_apply(v[e], s);
    out4[i] = v;
  }
}

// LayerNorm: pass1 amax; pass2 store f16 codes
template<bool STORE>
__global__ __launch_bounds__(64) void k_ln(const float* __restrict__ x,
    const float* __restrict__ g, const float* __restrict__ b,
    f16_t* __restrict__ y16, const float* scale_slot, float* amax_slot){
  int row = blockIdx.x, lane = threadIdx.x;
  const float* xr = x + (long)row * C_;
  float v[12]; float s = 0.0f;
  #pragma unroll
  for (int i = 0; i < 12; ++i){ v[i] = xr[lane + 64*i]; s += v[i]; }
  s = wred_sum(s);
  float mean = s / 768.0f;
  float q = 0.0f;
  #pragma unroll
  for (int i = 0; i < 12; ++i){ float d = v[i] - mean; q += d*d; }
  q = wred_sum(q);
  float inv = rsqrtf(q / 768.0f + 1e-6f);
  if (STORE){
    float fs = fq_scale(*scale_slot);
    f16_t* yr = y16 + (long)row * C_;
    #pragma unroll
    for (int i = 0; i < 12; ++i){
      int c = lane + 64*i;
      float o = (v[i] - mean) * inv * g[c] + b[c];
      yr[c] = (f16_t)fq_q(o, fs);
    }
  } else {
    float mx = 0.0f;
    #pragma unroll
    for (int i = 0; i < 12; ++i){
      int c = lane + 64*i;
      float o = (v[i] - mean) * inv * g[c] + b[c];
      mx = fmaxf(mx, fabsf(o));
    }
    mx = wred_max(mx);
    if (lane == 0) atomicMaxPosF(amax_slot, mx);
  }
}

template<bool FQRAW>
__global__ __launch_bounds__(256) void k_res(float* __restrict__ raw, const float* amax_raw,
                      const float* __restrict__ xin, float* amax_out, long n4){
  float s = 0.0f;
  if (FQRAW) s = fq_scale(*amax_raw);
  long i = (long)blockIdx.x * blockDim.x + threadIdx.x;
  long st = (long)gridDim.x * blockDim.x;
  f32x4* raw4 = (f32x4*)raw;
  const f32x4* xin4 = (const f32x4*)xin;
  float mx = 0.0f;
  for (; i < n4; i += st){
    f32x4 v = raw4[i];
    f32x4 xv = xin4[i];
    #pragma unroll
    for (int e = 0; e < 4; ++e){
      float t = FQRAW ? fq_apply(v[e], s) : v[e];
      float r = xv[e] + t;
      v[e] = r;
      mx = fmaxf(mx, fabsf(r));
    }
    raw4[i] = v;
  }
  block_amax_commit(mx, amax_out);
}

// ---------------- code GEMM: val = (A16 codes . W codes)*sA*sW + bias ----------------
// A16/W: f16 codes; 128x128 tile, 4 waves, BK=32; staging via global_load_lds (16B/lane)
template<int EPI>
__global__ __launch_bounds__(256) void k_gemm(const f16_t* __restrict__ A16,
    const f16_t* __restrict__ W, const float* __restrict__ bias,
    float* __restrict__ Cf, signed char* __restrict__ C8, f16_t* __restrict__ C16,
    const float* __restrict__ sA, const float* __restrict__ sW,
    const float* __restrict__ sOut, float* __restrict__ amax_slot,
    int Mv, int N, int K){
  __shared__ __align__(16) f16_t As[128*LS];
  __shared__ __align__(16) f16_t Ws[128*LS];
  const int bm = blockIdx.y * 128, bn = blockIdx.x * 128;
  const int t = threadIdx.x;
  const int lane = t & 63;
  const int wave = t >> 6;
  const int wr = (wave >> 1) * 64, wc = (wave & 1) * 64;
  const int lr = lane & 15, lkb = (lane >> 4) * 8;
  const int srow = lane >> 2;          // staging row within 16-row group
  const int scol = (lane & 3) * 8;     // staging col (f16)
  f32x4 acc[4][4] = {};
  for (int k0 = 0; k0 < K; k0 += 32){
    __syncthreads();
    {
      int rb = wave * 32;
      gload16(&A16[(long)(bm + rb      + srow)*K + k0 + scol], &As[(rb     )*LS]);
      gload16(&A16[(long)(bm + rb + 16 + srow)*K + k0 + scol], &As[(rb + 16)*LS]);
      gload16(&W [(long)(bn + rb      + srow)*K + k0 + scol], &Ws[(rb     )*LS]);
      gload16(&W [(long)(bn + rb + 16 + srow)*K + k0 + scol], &Ws[(rb + 16)*LS]);
    }
    __syncthreads();
    f16x8 af[4], wf[4];
    #pragma unroll
    for (int i = 0; i < 4; ++i){
      af[i] = *(const f16x8*)&As[(wr + i*16 + lr)*LS + lkb];
      wf[i] = *(const f16x8*)&Ws[(wc + i*16 + lr)*LS + lkb];
    }
    #pragma unroll
    for (int mf = 0; mf < 4; ++mf)
      #pragma unroll
      for (int nf = 0; nf < 4; ++nf)
        acc[mf][nf] = MFMA_F16(af[mf], wf[nf], acc[mf][nf], 0, 0, 0);
  }
  const float sc = fq_scale(*sA) * fq_scale(*sW);
  float fs = 0.0f;
  if (EPI == EPI_CODE8 || EPI == EPI_GCODE16) fs = fq_scale(*sOut);
  float mx = 0.0f;
  const int rl = (lane >> 4) * 4;
  #pragma unroll
  for (int mf = 0; mf < 4; ++mf){
    #pragma unroll
    for (int j = 0; j < 4; ++j){
      int row = bm + wr + mf*16 + rl + j;
      bool valid = row < Mv;
      #pragma unroll
      for (int nf = 0; nf < 4; ++nf){
        int col = bn + wc + nf*16 + lr;
        float v = acc[mf][nf][j] * sc + bias[col];
        if (EPI == EPI_AMX){
          if (valid) mx = fmaxf(mx, fabsf(v));
        } else if (EPI == EPI_VMAX){
          if (valid) mx = fmaxf(mx, v);          // pre-gelu signed max; no erff here
        } else if (EPI == EPI_CODE8){
          if (valid) C8[(long)row*N + col] = (signed char)(int)fq_q(v, fs);
        } else if (EPI == EPI_GCODE16){
          float o = valid ? fq_q(gelu_f(v), fs) : 0.0f;
          C16[(long)row*N + col] = (f16_t)o;     // zero pads for fc2
        } else if (EPI == EPI_F32){
          if (valid) Cf[(long)row*N + col] = v;
        }
      }
    }
  }
  if (EPI == EPI_AMX || EPI == EPI_VMAX){
    mx = wred_max(mx);
    if (lane == 0) atomicMaxPosF(amax_slot, mx);
  }
}

// ---------------- proj GEMM: A = exact integer I via hi/lo f16 planes ----------------
__global__ __launch_bounds__(256) void k_gemmp(const f16_t* __restrict__ Ahi,
    const f16_t* __restrict__ Alo, const f16_t* __restrict__ W,
    const float* __restrict__ bias, float* __restrict__ Cf,
    const unsigned int* __restrict__ lmin_slot, const float* __restrict__ sQkv,
    const float* __restrict__ sW, float* __restrict__ amax_slot,
    int Mv, int N, int K){
  __shared__ __align__(16) f16_t Ah[128*LS];
  __shared__ __align__(16) f16_t Al[128*LS];
  __shared__ __align__(16) f16_t Ws[128*LS];
  const int bm = blockIdx.y * 128, bn = blockIdx.x * 128;
  const int t = threadIdx.x;
  const int lane = t & 63;
  const int wave = t >> 6;
  const int wr = (wave >> 1) * 64, wc = (wave & 1) * 64;
  const int lr = lane & 15, lkb = (lane >> 4) * 8;
  const int srow = lane >> 2;
  const int scol = (lane & 3) * 8;
  f32x4 acc[4][4] = {};
  for (int k0 = 0; k0 < K; k0 += 32){
    __syncthreads();
    {
      int rb = wave * 32;
      gload16(&Ahi[(long)(bm + rb      + srow)*K + k0 + scol], &Ah[(rb     )*LS]);
      gload16(&Ahi[(long)(bm + rb + 16 + srow)*K + k0 + scol], &Ah[(rb + 16)*LS]);
      gload16(&Alo[(long)(bm + rb      + srow)*K + k0 + scol], &Al[(rb     )*LS]);
      gload16(&Alo[(long)(bm + rb + 16 + srow)*K + k0 + scol], &Al[(rb + 16)*LS]);
      gload16(&W  [(long)(bn + rb      + srow)*K + k0 + scol], &Ws[(rb     )*LS]);
      gload16(&W  [(long)(bn + rb + 16 + srow)*K + k0 + scol], &Ws[(rb + 16)*LS]);
    }
    __syncthreads();
    f16x8 ah[4], al[4], wf[4];
    #pragma unroll
    for (int i = 0; i < 4; ++i){
      ah[i] = *(const f16x8*)&Ah[(wr + i*16 + lr)*LS + lkb];
      al[i] = *(const f16x8*)&Al[(wr + i*16 + lr)*LS + lkb];
      wf[i] = *(const f16x8*)&Ws[(wc + i*16 + lr)*LS + lkb];
    }
    #pragma unroll
    for (int mf = 0; mf < 4; ++mf)
      #pragma unroll
      for (int nf = 0; nf < 4; ++nf){
        acc[mf][nf] = MFMA_F16(ah[mf], wf[nf], acc[mf][nf], 0, 0, 0);
        acc[mf][nf] = MFMA_F16(al[mf], wf[nf], acc[mf][nf], 0, 0, 0);
      }
  }
  float sa_p = (1.0f / __uint_as_float(*lmin_slot)) / 127.0f + 1e-8f;
  const float cs = sa_p * fq_scale(*sQkv) * fq_scale(*sW) * 2048.0f;
  float mx = 0.0f;
  const int rl = (lane >> 4) * 4;
  #pragma unroll
  for (int mf = 0; mf < 4; ++mf){
    #pragma unroll
    for (int j = 0; j < 4; ++j){
      int row = bm + wr + mf*16 + rl + j;
      if (row < Mv){
        #pragma unroll
        for (int nf = 0; nf < 4; ++nf){
          int col = bn + wc + nf*16 + lr;
          float v = acc[mf][nf][j] * cs + bias[col];
          Cf[(long)row*N + col] = v;
          mx = fmaxf(mx, fabsf(v));
        }
      }
    }
  }
  mx = wred_max(mx);
  if (lane == 0) atomicMaxPosF(amax_slot, mx);
}

// ---------------- V transpose ----------------
__global__ __launch_bounds__(64) void k_vtrans(const signed char* __restrict__ qkv8,
                                               f16_t* __restrict__ vt){
  int bh = blockIdx.x; int b = bh / H_, h = bh % H_, d = threadIdx.x;
  long coff = 1536 + h*64 + d;
  for (int m8 = 0; m8 < NKP/8; ++m8){
    f16_t vv[8];
    #pragma unroll
    for (int e = 0; e < 8; ++e){
      int m = m8*8 + e;
      signed char code = (m < N_TOK) ? qkv8[(long)(b*N_TOK + m)*2304 + coff] : (signed char)0;
      vv[e] = (f16_t)(short)code;
    }
    *(f16x8*)&vt[((long)bh*DH + d)*NKP + m8*8] = *(f16x8*)vv;
  }
}

// ---------------- attention pass1 ----------------
__global__ __launch_bounds__(64) void k_attn1(const signed char* __restrict__ qkv8,
    const float* __restrict__ sQkv, float* __restrict__ marr,
    float* __restrict__ larr, unsigned int* lmin_slot){
  int rt = blockIdx.x, bh = blockIdx.y;
  int b = bh / H_, h = bh % H_;
  int lane = threadIdx.x, lr = lane & 15, lkb = (lane >> 4) * 8;
  float sq = fq_scale(*sQkv);
  float s2 = sq * sq * 0.125f;
  int qn = rt*16 + lr; if (qn > N_TOK-1) qn = N_TOK-1;
  long qoff = (long)(b*N_TOK + qn)*2304 + h*64 + lkb;
  f16x8 a0 = cvt_i8_f16(*(const i8x8*)&qkv8[qoff]);
  f16x8 a1 = cvt_i8_f16(*(const i8x8*)&qkv8[qoff + 32]);
  float m[4], l[4];
  #pragma unroll
  for (int j = 0; j < 4; ++j){ m[j] = -1e30f; l[j] = 0.0f; }
  for (int ct = 0; ct < NKP/16; ++ct){
    int kn = ct*16 + lr; int knc = kn > N_TOK-1 ? N_TOK-1 : kn;
    long koff = (long)(b*N_TOK + knc)*2304 + 768 + h*64 + lkb;
    f16x8 b0 = cvt_i8_f16(*(const i8x8*)&qkv8[koff]);
    f16x8 b1 = cvt_i8_f16(*(const i8x8*)&qkv8[koff + 32]);
    f32x4 sacc = {};
    sacc = MFMA_F16(a0, b0, sacc, 0, 0, 0);
    sacc = MFMA_F16(a1, b1, sacc, 0, 0, 0);
    bool cv = kn < N_TOK;
    #pragma unroll
    for (int j = 0; j < 4; ++j){
      float sv = cv ? sacc[j]*s2 : -1e30f;
      float mn = fmaxf(m[j], sv);
      l[j] = l[j]*expf(m[j]-mn) + expf(sv-mn);
      m[j] = mn;
    }
  }
  #pragma unroll
  for (int mask = 1; mask < 16; mask <<= 1){
    #pragma unroll
    for (int j = 0; j < 4; ++j){
      float mo = __shfl_xor(m[j], mask);
      float lo = __shfl_xor(l[j], mask);
      float mn = fmaxf(m[j], mo);
      l[j] = l[j]*expf(m[j]-mn) + lo*expf(mo-mn);
      m[j] = mn;
    }
  }
  float lmn = 3.4e38f;
  #pragma unroll
  for (int j = 0; j < 4; ++j){
    int r = rt*16 + (lane >> 4)*4 + j;
    if (r < N_TOK) lmn = fminf(lmn, l[j]);
    if (lr == 0 && r < NP){ marr[(long)bh*NP + r] = m[j]; larr[(long)bh*NP + r] = l[j]; }
  }
  lmn = wred_min(lmn);
  if (lane == 0) atomicMin(lmin_slot, __float_as_uint(lmn));
}

// ---------------- attention pass2 + PV ----------------
__global__ __launch_bounds__(64) void k_attn2pv(const signed char* __restrict__ qkv8,
    const f16_t* __restrict__ vt, const float* __restrict__ sQkv,
    const float* __restrict__ marr, const float* __restrict__ larr,
    const unsigned int* lmin_slot, f16_t* __restrict__ xa_hi, f16_t* __restrict__ xa_lo){
  __shared__ __align__(16) f16_t Pl[16*PLDS];
  int rt = blockIdx.x, bh = blockIdx.y;
  int b = bh / H_, h = bh % H_;
  int lane = threadIdx.x, lr = lane & 15, lkb = (lane >> 4) * 8;
  float sq = fq_scale(*sQkv);
  float s2 = sq * sq * 0.125f;
  float lmin = __uint_as_float(*lmin_slot);
  float sa = (1.0f / lmin) / 127.0f + 1e-8f;
  int qn = rt*16 + lr; if (qn > N_TOK-1) qn = N_TOK-1;
  long qoff = (long)(b*N_TOK + qn)*2304 + h*64 + lkb;
  f16x8 a0 = cvt_i8_f16(*(const i8x8*)&qkv8[qoff]);
  f16x8 a1 = cvt_i8_f16(*(const i8x8*)&qkv8[qoff + 32]);
  int rbase = (lane >> 4)*4;
  float pm[4], pinv[4];
  #pragma unroll
  for (int j = 0; j < 4; ++j){
    int r = rt*16 + rbase + j;
    pm[j] = marr[(long)bh*NP + r];
    pinv[j] = 1.0f / larr[(long)bh*NP + r];
  }
  for (int ct = 0; ct < NKP/16; ++ct){
    int kn = ct*16 + lr; int knc = kn > N_TOK-1 ? N_TOK-1 : kn;
    long koff = (long)(b*N_TOK + knc)*2304 + 768 + h*64 + lkb;
    f16x8 b0 = cvt_i8_f16(*(const i8x8*)&qkv8[koff]);
    f16x8 b1 = cvt_i8_f16(*(const i8x8*)&qkv8[koff + 32]);
    f32x4 sacc = {};
    sacc = MFMA_F16(a0, b0, sacc, 0, 0, 0);
    sacc = MFMA_F16(a1, b1, sacc, 0, 0, 0);
    bool cv = kn < N_TOK;
    #pragma unroll
    for (int j = 0; j < 4; ++j){
      int r = rt*16 + rbase + j;
      float p = 0.0f;
      if (cv && r < N_TOK) p = expf(sacc[j]*s2 - pm[j]) * pinv[j];
      float qp = fminf(rintf(p / sa), 127.0f);
      Pl[(rbase + j)*PLDS + ct*16 + lr] = (f16_t)qp;
    }
  }
  __syncthreads();
  f32x4 acc[4] = {};
  for (int k0 = 0; k0 < NKP; k0 += 32){
    f16x8 a = *(const f16x8*)&Pl[lr*PLDS + k0 + lkb];
    #pragma unroll
    for (int nf = 0; nf < 4; ++nf){
      f16x8 bb = *(const f16x8*)&vt[((long)bh*DH + nf*16 + lr)*NKP + k0 + lkb];
      acc[nf] = MFMA_F16(a, bb, acc[nf], 0, 0, 0);
    }
  }
  #pragma unroll
  for (int j = 0; j < 4; ++j){
    int n = rt*16 + rbase + j;
    if (n < N_TOK){
      long orow = (long)(b*N_TOK + n)*C_ + h*DH;
      #pragma unroll
      for (int nf = 0; nf < 4; ++nf){
        float I  = acc[nf][j];
        float hi = rintf(I * (1.0f/2048.0f));
        float lo = (I - hi * 2048.0f) * (1.0f/2048.0f);
        xa_hi[orow + nf*16 + lr] = (f16_t)hi;
        xa_lo[orow + nf*16 + lr] = (f16_t)lo;
      }
    }
  }
}

// ---------------- host ----------------
static inline int cdiv_i(long a, long b){ return (int)((a + b - 1) / b); }

extern "C" void kernel_launch(void* const* d_in, const int* in_sizes, int n_in,
                              void* d_out, int out_size, void* d_ws, size_t ws_size,
                              hipStream_t stream){
  const float* x      = (const float*)d_in[0];
  const float* w_qkv  = (const float*)d_in[1];
  const float* b_qkv  = (const float*)d_in[2];
  const float* w_proj = (const float*)d_in[3];
  const float* b_proj = (const float*)d_in[4];
  const float* w_fc1  = (const float*)d_in[5];
  const float* b_fc1  = (const float*)d_in[6];
  const float* w_fc2  = (const float*)d_in[7];
  const float* b_fc2  = (const float*)d_in[8];
  const float* g1     = (const float*)d_in[9];
  const float* be1    = (const float*)d_in[10];
  const float* g2     = (const float*)d_in[11];
  const float* be2    = (const float*)d_in[12];
  float* out = (float*)d_out;

  // ---- workspace (150,209,536 B == round-5-proven footprint) ----
  char* ws = (char*)d_ws;
  size_t off = 0;
  float* slots  = (float*)ws;              off += 1024;
  f16_t* wqkv_c = (f16_t*)(ws + off);      off += (size_t)2304*768*2;
  f16_t* wproj_c= (f16_t*)(ws + off);      off += (size_t)768*768*2;
  f16_t* wfc1_c = (f16_t*)(ws + off);      off += (size_t)3072*768*2;
  f16_t* wfc2_c = (f16_t*)(ws + off);      off += (size_t)768*3072*2;
  f16_t* xn16   = (f16_t*)(ws + off);      off += (size_t)M_PAD*C_*2;   // LN codes f16
  char* r1 = ws + off;
  // attn phase
  signed char* qkv8 = (signed char*)r1;                                // 29.05 MB
  f16_t* vtb  = (f16_t*)(r1 + (size_t)M_VALID*2304);                   // 22.02 MB
  float* marr = (float*)(r1 + (size_t)M_VALID*2304 + (size_t)BH*DH*NKP*2);
  float* larr = marr + (size_t)BH*NP;
  size_t xa_off = (size_t)M_VALID*2304 + (size_t)BH*DH*NKP*2 + 2*(size_t)BH*NP*4;
  f16_t* xa_hi = (f16_t*)(r1 + xa_off);
  f16_t* xa_lo = (f16_t*)(r1 + xa_off + (size_t)M_PAD*C_*2);
  size_t attn_sz = xa_off + 2*(size_t)M_PAD*C_*2;                      // 91.3 MB
  // mlp phase (overlays dead attn buffers)
  float* x1 = (float*)r1;                                              // 38.73 MB
  f16_t* h16 = (f16_t*)(r1 + (size_t)M_VALID*C_*4);                    // 77.86 MB
  size_t mlp_sz = (size_t)M_VALID*C_*4 + (size_t)M_PAD*DFF*2;          // 116.6 MB
  off += (attn_sz > mlp_sz ? attn_sz : mlp_sz);
  const size_t NEED = off;

  if (ws_size < NEED){
    k_fill<<<256, 256, 0, stream>>>(out, out_size, 1.0e4f);  // sentinel
    return;
  }

  const long nW1 = (long)2304*768, nW2 = (long)768*768, nW3 = (long)3072*768, nW4 = (long)768*3072;
  const long nXC = (long)M_VALID*C_;
  const long nXC4 = nXC/4;
  float* raw = out;   // d_out doubles as f32 raw buffer

  k_init<<<1, 64, 0, stream>>>(slots);
  hipMemsetAsync(xn16 + (size_t)M_VALID*C_, 0, (size_t)(M_PAD - M_VALID)*C_*2, stream);
  hipMemsetAsync(xa_hi + (size_t)M_VALID*C_, 0, (size_t)(M_PAD - M_VALID)*C_*2, stream);
  hipMemsetAsync(xa_lo + (size_t)M_VALID*C_, 0, (size_t)(M_PAD - M_VALID)*C_*2, stream);

  // weight codes
  k_amax<<<1024, 256, 0, stream>>>(w_qkv, nW1/4, &slots[S_WQKV]);
  k_amax<<<512, 256, 0, stream>>>(w_proj, nW2/4, &slots[S_WPROJ]);
  k_amax<<<1024, 256, 0, stream>>>(w_fc1, nW3/4, &slots[S_WFC1]);
  k_amax<<<1024, 256, 0, stream>>>(w_fc2, nW4/4, &slots[S_WFC2]);
  k_wcode<<<cdiv_i(nW1,256), 256, 0, stream>>>(w_qkv, wqkv_c, &slots[S_WQKV], nW1);
  k_wcode<<<cdiv_i(nW2,256), 256, 0, stream>>>(w_proj, wproj_c, &slots[S_WPROJ], nW2);
  k_wcode<<<cdiv_i(nW3,256), 256, 0, stream>>>(w_fc1, wfc1_c, &slots[S_WFC1], nW3);
  k_wcode<<<cdiv_i(nW4,256), 256, 0, stream>>>(w_fc2, wfc2_c, &slots[S_WFC2], nW4);

  // norm1 -> xn16 codes
  k_ln<false><<<M_VALID, 64, 0, stream>>>(x, g1, be1, nullptr, nullptr, &slots[S_LN1]);
  k_ln<true ><<<M_VALID, 64, 0, stream>>>(x, g1, be1, xn16, &slots[S_LN1], nullptr);

  // qkv: amax pass then code pass (i8 out for attention)
  k_gemm<EPI_AMX><<<dim3(18, 99), 256, 0, stream>>>(xn16, wqkv_c, b_qkv,
      nullptr, nullptr, nullptr, &slots[S_LN1], &slots[S_WQKV], nullptr, &slots[S_QKV], M_VALID, 2304, 768);
  k_gemm<EPI_CODE8><<<dim3(18, 99), 256, 0, stream>>>(xn16, wqkv_c, b_qkv,
      nullptr, qkv8, nullptr, &slots[S_LN1], &slots[S_WQKV], &slots[S_QKV], nullptr, M_VALID, 2304, 768);

  // attention
  k_vtrans<<<BH, 64, 0, stream>>>(qkv8, vtb);
  k_attn1<<<dim3(NP/16, BH), 64, 0, stream>>>(qkv8, &slots[S_QKV], marr, larr,
      (unsigned int*)&slots[S_LMIN]);
  k_attn2pv<<<dim3(NP/16, BH), 64, 0, stream>>>(qkv8, vtb, &slots[S_QKV], marr, larr,
      (const unsigned int*)&slots[S_LMIN], xa_hi, xa_lo);

  // proj (exact I) -> raw(=out) + amax; residual1; fq -> x1
  k_gemmp<<<dim3(6, 99), 256, 0, stream>>>(xa_hi, xa_lo, wproj_c, b_proj, raw,
      (const unsigned int*)&slots[S_LMIN], &slots[S_QKV], &slots[S_WPROJ], &slots[S_PROJ],
      M_VALID, 768, 768);
  k_res<true><<<1040, 256, 0, stream>>>(raw, &slots[S_PROJ], x, &slots[S_R1], nXC4);
  k_fq_f32<<<2080, 256, 0, stream>>>(raw, x1, &slots[S_R1], nXC4);

  // norm2 -> xn16 codes
  k_ln<false><<<M_VALID, 64, 0, stream>>>(x1, g2, be2, nullptr, nullptr, &slots[S_LN2]);
  k_ln<true ><<<M_VALID, 64, 0, stream>>>(x1, g2, be2, xn16, &slots[S_LN2], nullptr);

  // fc1: vmax pass (no erff), slot -> gelu amax, then gelu-code pass -> h16
  k_gemm<EPI_VMAX><<<dim3(24, 99), 256, 0, stream>>>(xn16, wfc1_c, b_fc1,
      nullptr, nullptr, nullptr, &slots[S_LN2], &slots[S_WFC1], nullptr, &slots[S_GELU], M_VALID, 3072, 768);
  k_gelu_amax<<<1, 1, 0, stream>>>(&slots[S_GELU]);
  k_gemm<EPI_GCODE16><<<dim3(24, 99), 256, 0, stream>>>(xn16, wfc1_c, b_fc1,
      nullptr, nullptr, h16, &slots[S_LN2], &slots[S_WFC1], &slots[S_GELU], nullptr, M_VALID, 3072, 768);

  // fc2 -> raw(=out); residual2; final fq
  k_gemm<EPI_F32><<<dim3(6, 99), 256, 0, stream>>>(h16, wfc2_c, b_fc2,
      raw, nullptr, nullptr, &slots[S_GELU], &slots[S_WFC2], nullptr, nullptr, M_VALID, 768, 3072);
  k_res<false><<<1040, 256, 0, stream>>>(raw, nullptr, x1, &slots[S_R2], nXC4);
  k_fq_f32<<<2080, 256, 0, stream>>>(raw, out, &slots[S_R2], nXC4);
}